// Round 22
// baseline (352.321 us; speedup 1.0000x reference)
//
#include <hip/hip_runtime.h>
#include <cstdint>
#include <cmath>

#define BATCH 64

typedef __attribute__((ext_vector_type(8))) __bf16 bf16x8;
typedef __attribute__((ext_vector_type(16))) float f32x16;

// ---------------------------------------------------------------------------
// Spline + silu expansion: x -> [silu(x), B_0(x) .. B_7(x)]
// ---------------------------------------------------------------------------
__device__ __forceinline__ void expand9(float x, float* e) {
  float t = __expf(-x);
  e[0] = __fdividef(x, 1.f + t);  // silu
  float b[11];
#pragma unroll
  for (int j = 0; j < 11; ++j) {
    float gj  = 0.4f * (float)j - 2.2f;
    float gj1 = 0.4f * (float)(j + 1) - 2.2f;
    b[j] = (x >= gj && x < gj1) ? 1.f : 0.f;
  }
#pragma unroll
  for (int k = 1; k <= 3; ++k) {
    float inv = 1.f / (0.4f * (float)k);
#pragma unroll
    for (int j = 0; j < 11 - k; ++j) {
      float gj   = 0.4f * (float)j - 2.2f;
      float gjk1 = 0.4f * (float)(j + k + 1) - 2.2f;
      b[j] = ((x - gj) * b[j] + (gjk1 - x) * b[j + 1]) * inv;
    }
  }
#pragma unroll
  for (int v = 0; v < 8; ++v) e[v + 1] = b[v];
}

// bf16 split helpers (round-to-nearest-even)
__device__ __forceinline__ unsigned short f2bf(float x) {
  uint32_t u = __float_as_uint(x);
  uint32_t r = u + 0x7fffu + ((u >> 16) & 1u);
  return (unsigned short)(r >> 16);
}
__device__ __forceinline__ float bf2f(unsigned short h) {
  return __uint_as_float(((uint32_t)h) << 16);
}
__device__ __forceinline__ uint32_t packsplit(float x) {
  unsigned short hi = f2bf(x);
  unsigned short lo = f2bf(x - bf2f(hi));
  return (uint32_t)hi | ((uint32_t)lo << 16);
}

// ---------------------------------------------------------------------------
// Prep bodies (identical math to round 21, as device functions on bid)
// ---------------------------------------------------------------------------
template <int F, int N>
__device__ __forceinline__ void bpack_body(int bid, const float* __restrict__ bw,
                                           const float* __restrict__ sw,
                                           const float* __restrict__ ss,
                                           unsigned short* __restrict__ Bg) {
  int idx = bid * 256 + threadIdx.x;
  int fl = idx & 15;
  int n = (idx >> 4) & (N - 1);
  int rest = idx >> 4;
  rest /= N;
  int v = rest % 9;
  int kc = rest / 9;
  int f = kc * 16 + fl;
  size_t src = (size_t)n * F + f;
  float wv = (v == 0) ? bw[src] : sw[src * 8 + (v - 1)] * ss[src];
  Bg[((size_t)kc * 9 + v) * N * 16 + (size_t)n * 16 + fl] = f2bf(wv);
}

__device__ __forceinline__ void wnl4_body(int bid, const float* __restrict__ bw,
                                          const float* __restrict__ sw,
                                          const float* __restrict__ ss,
                                          float* __restrict__ Wn) {
  int idx = bid * 256 + threadIdx.x;  // 27648 exactly
  if (idx >= 27648) return;
  int u = idx % 27;
  int o = u % 3, v = u / 3;
  int rest = idx / 27;
  int nb = rest & 3;
  rest >>= 2;
  int pc = rest & 3;
  rest >>= 2;
  int c = rest;
  int PH = pc >> 1, PW = pc & 1;
  int a = nb >> 1, b2 = nb & 1;
  float s = 0.f;
#pragma unroll
  for (int kh = 0; kh < 3; ++kh) {
    if (((kh > PH) ? 1 : 0) != a) continue;
#pragma unroll
    for (int kw = 0; kw < 3; ++kw) {
      if (((kw > PW) ? 1 : 0) != b2) continue;
      int f = c * 9 + kh * 3 + kw;
      float wv = (v == 0)
                     ? bw[o * 576 + f]
                     : sw[((size_t)(o * 576 + f)) * 8 + (v - 1)] * ss[o * 576 + f];
      s += wv;
    }
  }
  Wn[idx] = s;
}

__device__ __forceinline__ void linear_body(int bid, const float* __restrict__ x,
                                            const float* __restrict__ w,
                                            const float* __restrict__ bias,
                                            float* __restrict__ h,
                                            uint32_t* __restrict__ E) {
  int idx = bid * 256 + threadIdx.x;  // 64*2048
  int b = idx >> 11, o = idx & 2047;
  const float* xr = x + b * 100;
  const float* wr = w + o * 100;
  float acc = bias[o];
#pragma unroll 4
  for (int k = 0; k < 100; ++k) acc += xr[k] * wr[k];
  float hv = fmaxf(acc, 0.f);
  h[idx] = hv;
  float e[9];
  expand9(hv, e);
  uint32_t u0 = packsplit(e[0]), u1 = packsplit(e[1]), u2 = packsplit(e[2]);
  uint32_t u3 = packsplit(e[3]), u4 = packsplit(e[4]), u5 = packsplit(e[5]);
  uint32_t u6 = packsplit(e[6]), u7 = packsplit(e[7]), u8 = packsplit(e[8]);
  uint4* p = reinterpret_cast<uint4*>(E + (size_t)idx * 12);
  p[0] = make_uint4(u0, u1, u2, u3);
  p[1] = make_uint4(u4, u5, u6, u7);
  p[2] = make_uint4(u8, 0u, 0u, 0u);
}

// One launch for ALL input-only prep (round 22): 3x bpack + wnl4 + linear.
__global__ __launch_bounds__(256) void prep_all(
    const float* __restrict__ x, const float* __restrict__ lin_w,
    const float* __restrict__ lin_b, float* __restrict__ h,
    uint32_t* __restrict__ Eg,
    const float* __restrict__ bw1, const float* __restrict__ sw1,
    const float* __restrict__ ss1, unsigned short* __restrict__ Bg1,
    const float* __restrict__ bw2, const float* __restrict__ sw2,
    const float* __restrict__ ss2, unsigned short* __restrict__ Bg2,
    const float* __restrict__ bw3, const float* __restrict__ sw3,
    const float* __restrict__ ss3, unsigned short* __restrict__ Bg3,
    const float* __restrict__ bw4, const float* __restrict__ sw4,
    const float* __restrict__ ss4, float* __restrict__ wl4) {
  int bid = blockIdx.x;
  if (bid < 41472) { bpack_body<4608, 256>(bid, bw1, sw1, ss1, Bg1); return; }
  bid -= 41472;
  if (bid < 10368) { bpack_body<2304, 128>(bid, bw2, sw2, ss2, Bg2); return; }
  bid -= 10368;
  if (bid < 2592) { bpack_body<1152, 64>(bid, bw3, sw3, ss3, Bg3); return; }
  bid -= 2592;
  if (bid < 108) { wnl4_body(bid, bw4, sw4, ss4, wl4); return; }
  bid -= 108;
  linear_body(bid, x, lin_w, lin_b, h, Eg);
}

// Standalone linear kernel (fallback path only)
__global__ __launch_bounds__(256) void linear_relu_only(
    const float* __restrict__ x, const float* __restrict__ w,
    const float* __restrict__ bias, float* __restrict__ h) {
  int idx = blockIdx.x * 256 + threadIdx.x;
  int b = idx >> 11, o = idx & 2047;
  const float* xr = x + b * 100;
  const float* wr = w + o * 100;
  float acc = bias[o];
#pragma unroll 4
  for (int k = 0; k < 100; ++k) acc += xr[k] * wr[k];
  h[idx] = fmaxf(acc, 0.f);
}

// ---------------------------------------------------------------------------
// bf16 MFMA GEMM — round-19/21 proven config (SK=16/8/4, 1024 blocks, CPB=18).
// ---------------------------------------------------------------------------
template <int CIN, int COUT, int HO, int WO, int SK>
__global__ __launch_bounds__(256, 4) void gemm_mfma(
    const uint32_t* __restrict__ E, const unsigned short* __restrict__ Bg,
    float* __restrict__ part) {
  constexpr int F = CIN * 9;
  constexpr int NKC = F / 16;
  constexpr int HI = HO / 2, WI = WO / 2;
  constexpr int M = BATCH * HO * WO;
  constexpr int CPB = NKC / SK;
  static_assert(NKC % SK == 0, "sk");

  // plane 0: A-hi [9][64][16]; plane 1: B-hi
  __shared__ __align__(16) unsigned short lds[2 * 9216];

  const int t = threadIdx.x;
  const int mbase = blockIdx.x * 64;
  const int nb = blockIdx.y;
  const int kc0 = blockIdx.z * CPB;

  uint32_t ez[9];
  {
    float e0[9];
    expand9(0.f, e0);
#pragma unroll
    for (int v = 0; v < 9; ++v) ez[v] = packsplit(e0[v]);
  }

  const int lane = t & 63, wv_ = t >> 6;
  const int wm = wv_ >> 1, wn = wv_ & 1;
  const int frow = lane & 31, fkg = lane >> 5;
  const int aoff = ((wm * 32 + frow) * 16 + fkg * 8) * 2;  // bytes
  const int boff = ((wn * 32 + frow) * 16 + fkg * 8) * 2;

  // A-staging geometry: thread covers row aml, fl = flq*4..+3
  const int aml = t >> 2, flq = t & 3;
  const int am = mbase + aml;
  const int ab = am / (HO * WO), ahw = am % (HO * WO);
  const int ahh = ahw / WO, aww = ahw % WO;

  f32x16 acc;
#pragma unroll
  for (int i = 0; i < 16; ++i) acc[i] = 0.f;

  for (int ci = 0; ci < CPB; ++ci) {
    const int kc = kc0 + ci;
    __syncthreads();

    // ---- stage A (hi only): 4 taps/thread, 3 dwordx4 loads per tap ----
    {
      uint32_t w0[9], w1[9], w2[9], w3[9];
#define LDTAP(IDX, DST)                                                       \
  {                                                                           \
    int f = kc * 16 + flq * 4 + IDX;                                          \
    int c = f / 9, r = f - 9 * c;                                             \
    int kh = r / 3, kw = r - kh * 3;                                          \
    int hp = ahh + kh - 1, wp = aww + kw - 1;                                 \
    if ((unsigned)hp < (unsigned)HO && (unsigned)wp < (unsigned)WO) {         \
      const uint4* ep4 = reinterpret_cast<const uint4*>(                      \
          E + (size_t)(((ab * CIN + c) * HI + (hp >> 1)) * WI + (wp >> 1)) *  \
                  12);                                                        \
      uint4 q0 = ep4[0], q1 = ep4[1], q2 = ep4[2];                            \
      DST[0] = q0.x; DST[1] = q0.y; DST[2] = q0.z; DST[3] = q0.w;             \
      DST[4] = q1.x; DST[5] = q1.y; DST[6] = q1.z; DST[7] = q1.w;             \
      DST[8] = q2.x;                                                          \
    } else {                                                                  \
      _Pragma("unroll") for (int v = 0; v < 9; ++v) DST[v] = ez[v];           \
    }                                                                         \
  }
      LDTAP(0, w0)
      LDTAP(1, w1)
      LDTAP(2, w2)
      LDTAP(3, w3)
#undef LDTAP
      char* lb = reinterpret_cast<char*>(lds);
#pragma unroll
      for (int v = 0; v < 9; ++v) {
        uint32_t hi01 = (w0[v] & 0xffffu) | (w1[v] << 16);
        uint32_t hi23 = (w2[v] & 0xffffu) | (w3[v] << 16);
        *reinterpret_cast<uint2*>(lb + v * 2048 + aml * 32 + flq * 8) =
            make_uint2(hi01, hi23);
      }
    }

    // ---- stage B: one plane, 1152 float4s over 256 threads ----
    {
      const unsigned short* bsrc = Bg + (size_t)kc * (9 * COUT * 16);
#define STAGEB(U)                                                             \
  {                                                                           \
    int u = (U);                                                              \
    int v = u >> 7, q = u & 127;                                              \
    int nl = q >> 1, half = q & 1;                                            \
    size_t srcE = (size_t)v * (COUT * 16) + (size_t)(nb * 64 + nl) * 16 +     \
                  half * 8;                                                   \
    int dst = 9216 + v * 1024 + nl * 16 + half * 8;                           \
    *reinterpret_cast<float4*>(&lds[dst]) =                                   \
        *reinterpret_cast<const float4*>(&bsrc[srcE]);                        \
  }
      STAGEB(t)
      STAGEB(256 + t)
      STAGEB(512 + t)
      STAGEB(768 + t)
      if (t < 128) STAGEB(1024 + t)
#undef STAGEB
    }
    __syncthreads();

    // ---- compute: 9 v-steps x 1 product ----
#pragma unroll
    for (int v = 0; v < 9; ++v) {
      const char* lbc = reinterpret_cast<const char*>(lds);
      bf16x8 ah = *reinterpret_cast<const bf16x8*>(lbc + v * 2048 + aoff);
      bf16x8 bh =
          *reinterpret_cast<const bf16x8*>(lbc + 18432 + v * 2048 + boff);
      acc = __builtin_amdgcn_mfma_f32_32x32x16_bf16(ah, bh, acc, 0, 0, 0);
    }
  }

  // ---- epilogue: C/D layout col=lane&31, row=(reg&3)+8*(reg>>2)+4*(lane>>5)
  float* p = part + (size_t)blockIdx.z * M * COUT;
  const int gn = nb * 64 + wn * 32 + frow;
#pragma unroll
  for (int r = 0; r < 16; ++r) {
    int mlocal = (r & 3) + 8 * (r >> 2) + 4 * fkg;
    int gm = mbase + wm * 32 + mlocal;
    p[(size_t)gm * COUT + gn] = acc[r];
  }
}

// ---------------------------------------------------------------------------
// Reduce split-K partials -> activation; write packed 12-stride expansion E.
// ---------------------------------------------------------------------------
template <int COUT, int HO, int WO>
__global__ __launch_bounds__(256) void reduce_pe_pack(
    const float* __restrict__ part, uint32_t* __restrict__ E, int SK) {
  constexpr int M = BATCH * HO * WO;
  int idx = blockIdx.x * 256 + threadIdx.x;
  int ww = idx % WO;
  int tmp = idx / WO;
  int hh = tmp % HO;
  tmp /= HO;
  int o = tmp % COUT;
  int b = tmp / COUT;
  int m = (b * HO + hh) * WO + ww;
  float s = 0.f;
  for (int k = 0; k < SK; ++k) s += part[((size_t)k * M + m) * COUT + o];
  float e[9];
  expand9(s, e);
  uint32_t u0 = packsplit(e[0]), u1 = packsplit(e[1]), u2 = packsplit(e[2]);
  uint32_t u3 = packsplit(e[3]), u4 = packsplit(e[4]), u5 = packsplit(e[5]);
  uint32_t u6 = packsplit(e[6]), u7 = packsplit(e[7]), u8 = packsplit(e[8]);
  uint4* p = reinterpret_cast<uint4*>(E + (size_t)idx * 12);
  p[0] = make_uint4(u0, u1, u2, u3);
  p[1] = make_uint4(u4, u5, u6, u7);
  p[2] = make_uint4(u8, 0u, 0u, 0u);
}

template <int COUT, int HO, int WO>
__global__ __launch_bounds__(256) void reduce_p(
    const float* __restrict__ part, float* __restrict__ act, int SK) {
  constexpr int M = BATCH * HO * WO;
  int idx = blockIdx.x * 256 + threadIdx.x;
  int ww = idx % WO;
  int tmp = idx / WO;
  int hh = tmp % HO;
  tmp /= HO;
  int o = tmp % COUT;
  int b = tmp / COUT;
  int m = (b * HO + hh) * WO + ww;
  float s = 0.f;
  for (int k = 0; k < SK; ++k) s += part[((size_t)k * M + m) * COUT + o];
  act[idx] = s;
}

// ---------------------------------------------------------------------------
// L4 v8 (round-20/21 proven): 32 channel groups (2 ch/block, 2048 blocks).
// ---------------------------------------------------------------------------
template <int PH, int PW>
__device__ void l4v8_wave(const float* __restrict__ eLds,
                          const float* __restrict__ WnB,
                          const float* __restrict__ ez, int lane, int bb,
                          int cs, float* __restrict__ p4) {
  constexpr int PC = PH * 2 + PW;
  const int j = lane & 15;
  const int i0 = (lane >> 4) << 2;
#pragma unroll 1
  for (int q = 0; q < 4; ++q) {
    const int i = i0 + q;
    float acc[3] = {0.f, 0.f, 0.f};
#pragma unroll
    for (int a = 0; a < 2; ++a) {
      const int gi = i + PH - 1 + a;
      const bool vr = (unsigned)gi < 16u;
#pragma unroll
      for (int b2 = 0; b2 < 2; ++b2) {
        const int gj = j + PW - 1 + b2;
        const bool ok = vr && ((unsigned)gj < 16u);
        const int pp = ok ? (gi * 16 + gj) : 0;  // clamped safe address
        const int nbi = a * 2 + b2;
#pragma unroll
        for (int cl = 0; cl < 2; ++cl) {
          const float* ep = eLds + cl * 2304 + pp * 9;
          float en[9];
#pragma unroll
          for (int v = 0; v < 9; ++v) en[v] = ok ? ep[v] : ez[v];
          const float* wp = WnB + ((cl * 4 + PC) * 4 + nbi) * 27;
#pragma unroll
          for (int v = 0; v < 9; ++v) {
            acc[0] = fmaf(en[v], wp[v * 3 + 0], acc[0]);
            acc[1] = fmaf(en[v], wp[v * 3 + 1], acc[1]);
            acc[2] = fmaf(en[v], wp[v * 3 + 2], acc[2]);
          }
        }
      }
    }
    const int h = (i << 1) + PH, w = (j << 1) + PW;
#pragma unroll
    for (int o = 0; o < 3; ++o)
      p4[(size_t)cs * 196608 + ((bb * 3 + o) << 10) + (h << 5) + w] = acc[o];
  }
}

__global__ __launch_bounds__(256) void kan_l4_v8(
    const float* __restrict__ a3, const float* __restrict__ Wn,
    float* __restrict__ p4) {
  __shared__ float eLds[2 * 256 * 9];  // 18.4 KB
  const int bid = blockIdx.x;          // 64 bb x 32 cs
  const int bb = bid >> 5, cs = bid & 31;
  const int t = threadIdx.x;
  float ez[9];
  expand9(0.f, ez);
#pragma unroll
  for (int cl = 0; cl < 2; ++cl) {
    float x = a3[(size_t)(bb * 64 + cs * 2 + cl) * 256 + t];
    float ev[9];
    expand9(x, ev);
#pragma unroll
    for (int v = 0; v < 9; ++v) eLds[(cl * 256 + t) * 9 + v] = ev[v];
  }
  __syncthreads();
  const int wv_ = t >> 6, lane = t & 63;
  const float* WnB = Wn + (size_t)cs * 2 * (4 * 4 * 27);
  if (wv_ == 0)
    l4v8_wave<0, 0>(eLds, WnB, ez, lane, bb, cs, p4);
  else if (wv_ == 1)
    l4v8_wave<0, 1>(eLds, WnB, ez, lane, bb, cs, p4);
  else if (wv_ == 2)
    l4v8_wave<1, 0>(eLds, WnB, ez, lane, bb, cs, p4);
  else
    l4v8_wave<1, 1>(eLds, WnB, ez, lane, bb, cs, p4);
}

__global__ __launch_bounds__(256) void reduce_tanh_l4_32(
    const float* __restrict__ p4, float* __restrict__ out) {
  int i = blockIdx.x * 256 + threadIdx.x;  // 196608
  float s = 0.f;
#pragma unroll
  for (int k = 0; k < 32; ++k) s += p4[(size_t)k * 196608 + i];
  out[i] = tanhf(s);
}

__global__ __launch_bounds__(256) void reduce_tanh_l4(
    const float* __restrict__ p4, float* __restrict__ out) {
  int i = blockIdx.x * 256 + threadIdx.x;
  float s = p4[i] + p4[i + 196608] + p4[i + 2 * 196608] + p4[i + 3 * 196608];
  out[i] = tanhf(s);
}

// ---------------------------------------------------------------------------
// Fallback path (round-1 proven) for small workspace
// ---------------------------------------------------------------------------
template <int CIN, int COUT, int HO, int WO, int BN, int SK>
__global__ __launch_bounds__(256) void kan_gemm(
    const float* __restrict__ in, const float* __restrict__ bw,
    const float* __restrict__ sw, const float* __restrict__ ss,
    float* __restrict__ outp) {
  constexpr int BM = 64, TM = 4, TN = 4, FC = 16;
  constexpr int F = CIN * 9;
  constexpr int HI = HO / 2, WI = WO / 2;
  constexpr int M = BATCH * HO * WO;
  constexpr int FPB = F / SK;

  __shared__ float Ae[FC * 9][BM];

  const int t = threadIdx.x;
  const int mbase = blockIdx.x * BM;
  const int obase = blockIdx.y * BN;
  const int f0 = blockIdx.z * FPB;

  const int cg = t & (BN / TN - 1);
  const int rg = t / (BN / TN);
  const int m0 = rg * TM;
  const int o0 = obase + cg * TN;

  float acc[TM][TN] = {};

  for (int fc = f0; fc < f0 + FPB; fc += FC) {
#pragma unroll
    for (int j = 0; j < BM * FC / 256; ++j) {
      int p = j * 256 + t;
      int ml = p & (BM - 1);
      int df = p >> 6;
      int f = fc + df;
      int c = f / 9;
      int r = f - c * 9;
      int kh = r / 3, kw = r - kh * 3;
      int m = mbase + ml;
      int bb = m / (HO * WO);
      int rem = m % (HO * WO);
      int hh = rem / WO, ww = rem % WO;
      int hp = hh + kh - 1, wp = ww + kw - 1;
      float val = 0.f;
      if (hp >= 0 && hp < HO && wp >= 0 && wp < WO)
        val = in[((bb * CIN + c) * HI + (hp >> 1)) * WI + (wp >> 1)];
      float e[9];
      expand9(val, e);
#pragma unroll
      for (int v = 0; v < 9; ++v) Ae[df * 9 + v][ml] = e[v];
    }
    __syncthreads();

#pragma unroll 2
    for (int df = 0; df < FC; ++df) {
      int f = fc + df;
      float wb[TN], wsv[TN][8];
#pragma unroll
      for (int tn = 0; tn < TN; ++tn) {
        int i = (o0 + tn) * F + f;
        wb[tn] = bw[i];
        float sc = ss[i];
        const float4* sp = reinterpret_cast<const float4*>(sw + (size_t)i * 8);
        float4 s0 = sp[0], s1 = sp[1];
        wsv[tn][0] = s0.x * sc; wsv[tn][1] = s0.y * sc;
        wsv[tn][2] = s0.z * sc; wsv[tn][3] = s0.w * sc;
        wsv[tn][4] = s1.x * sc; wsv[tn][5] = s1.y * sc;
        wsv[tn][6] = s1.z * sc; wsv[tn][7] = s1.w * sc;
      }
      float a[9][TM];
#pragma unroll
      for (int v = 0; v < 9; ++v) {
        float4 q = *reinterpret_cast<const float4*>(&Ae[df * 9 + v][m0]);
        a[v][0] = q.x; a[v][1] = q.y; a[v][2] = q.z; a[v][3] = q.w;
      }
#pragma unroll
      for (int tm = 0; tm < TM; ++tm)
#pragma unroll
        for (int tn = 0; tn < TN; ++tn) acc[tm][tn] += a[0][tm] * wb[tn];
#pragma unroll
      for (int v = 1; v < 9; ++v)
#pragma unroll
        for (int tm = 0; tm < TM; ++tm)
#pragma unroll
          for (int tn = 0; tn < TN; ++tn)
            acc[tm][tn] += a[v][tm] * wsv[tn][v - 1];
    }
    __syncthreads();
  }

  if constexpr (SK > 1) {
    float* p = outp + (size_t)blockIdx.z * M * COUT;
#pragma unroll
    for (int tm = 0; tm < TM; ++tm) {
      int m = mbase + m0 + tm;
#pragma unroll
      for (int tn = 0; tn < TN; ++tn)
        p[(size_t)m * COUT + (o0 + tn)] = acc[tm][tn];
    }
  } else {
#pragma unroll
    for (int tm = 0; tm < TM; ++tm) {
      int m = mbase + m0 + tm;
      int bb = m / (HO * WO);
      int rem = m % (HO * WO);
      int hh = rem / WO, ww = rem % WO;
#pragma unroll
      for (int tn = 0; tn < TN; ++tn) {
        int o = o0 + tn;
        outp[((bb * COUT + o) * HO + hh) * WO + ww] = acc[tm][tn];
      }
    }
  }
}

template <int COUT, int HO, int WO, int SK>
__global__ __launch_bounds__(256) void reduce_partials_old(
    const float* __restrict__ part, float* __restrict__ act) {
  constexpr int M = BATCH * HO * WO;
  int idx = blockIdx.x * 256 + threadIdx.x;
  if (idx >= M * COUT) return;
  float s = 0.f;
#pragma unroll
  for (int k = 0; k < SK; ++k) s += part[(size_t)k * M * COUT + idx];
  int m = idx / COUT, o = idx - (idx / COUT) * COUT;
  int bb = m / (HO * WO);
  int rem = m % (HO * WO);
  int hh = rem / WO, ww = rem % WO;
  act[((bb * COUT + o) * HO + hh) * WO + ww] = s;
}

__global__ __launch_bounds__(256) void kan_l4_split(
    const float* __restrict__ a3, const float* __restrict__ bw,
    const float* __restrict__ sw, const float* __restrict__ ss,
    float* __restrict__ p4) {
  int tid = blockIdx.x * 256 + threadIdx.x;
  int cs = tid >> 16, pix = tid & 65535;
  int b = pix >> 10, rem = pix & 1023, h = rem >> 5, w = rem & 31;
  float acc[3] = {0.f, 0.f, 0.f};
  for (int c = cs * 16; c < cs * 16 + 16; ++c) {
#pragma unroll
    for (int kh = 0; kh < 3; ++kh) {
#pragma unroll
      for (int kw = 0; kw < 3; ++kw) {
        int f = (c * 3 + kh) * 3 + kw;
        int hp = h + kh - 1, wp = w + kw - 1;
        float x = 0.f;
        if ((unsigned)hp < 32u && (unsigned)wp < 32u)
          x = a3[((b * 64 + c) * 16 + (hp >> 1)) * 16 + (wp >> 1)];
        float e[9];
        expand9(x, e);
#pragma unroll
        for (int o = 0; o < 3; ++o) {
          int i = o * 576 + f;
          float d = e[1] * sw[i * 8 + 0];
#pragma unroll
          for (int v = 1; v < 8; ++v) d += e[v + 1] * sw[i * 8 + v];
          acc[o] += e[0] * bw[i] + d * ss[i];
        }
      }
    }
  }
#pragma unroll
  for (int o = 0; o < 3; ++o)
    p4[cs * 196608 + ((b * 3 + o) << 10) + (h << 5) + w] = acc[o];
}

// ---------------------------------------------------------------------------
extern "C" void kernel_launch(void* const* d_in, const int* in_sizes, int n_in,
                              void* d_out, int out_size, void* d_ws,
                              size_t ws_size, hipStream_t stream) {
  const float* x     = (const float*)d_in[0];
  const float* lin_w = (const float*)d_in[1];
  const float* lin_b = (const float*)d_in[2];
  const float* bw1 = (const float*)d_in[3];
  const float* sw1 = (const float*)d_in[4];
  const float* ss1 = (const float*)d_in[5];
  const float* bw2 = (const float*)d_in[6];
  const float* sw2 = (const float*)d_in[7];
  const float* ss2 = (const float*)d_in[8];
  const float* bw3 = (const float*)d_in[9];
  const float* sw3 = (const float*)d_in[10];
  const float* ss3 = (const float*)d_in[11];
  const float* bw4 = (const float*)d_in[12];
  const float* sw4 = (const float*)d_in[13];
  const float* ss4 = (const float*)d_in[14];

  float* wsf = (float*)d_ws;
  // ---- main-path layout (round 22): 18,660,352 floats = 74.6 MB ----
  float* h    = wsf;                                        // 131072
  float* a3   = wsf + 131072;                               // 1048576
  unsigned short* Bg1 = (unsigned short*)(wsf + 1179648);   // 5,308,416 floats
  unsigned short* Bg2 = (unsigned short*)(wsf + 6488064);   // 1,327,104 floats
  unsigned short* Bg3 = (unsigned short*)(wsf + 7815168);   //   331,776 floats
  float* wl4  = wsf + 8146944;                              //    27,648
  float* part = wsf + 8174592;                              // 4,194,304 (SK=16)
  uint32_t* Eg = (uint32_t*)(wsf + 12368896);               // 6,291,456 (12/pix)
  float* p4   = wsf + 12368896;  // aliases Eg (dead post-L3), 32*196608 floats

  const size_t mainNeed = 18660352ull;

  if (ws_size / 4 >= mainNeed) {
    // One launch for all input-only prep: 3x bpack + wnl4 + linear+expand.
    prep_all<<<55052, 256, 0, stream>>>(
        x, lin_w, lin_b, h, Eg,
        bw1, sw1, ss1, Bg1,
        bw2, sw2, ss2, Bg2,
        bw3, sw3, ss3, Bg3,
        bw4, sw4, ss4, wl4);

    // L1: CIN=512 COUT=256 4x4, SK=16 (1024 blocks, CPB=18)
    gemm_mfma<512, 256, 4, 4, 16>
        <<<dim3(16, 4, 16), 256, 0, stream>>>(Eg, Bg1, part);
    reduce_pe_pack<256, 4, 4><<<1024, 256, 0, stream>>>(part, Eg, 16);

    // L2: CIN=256 COUT=128 8x8, SK=8 (1024 blocks, CPB=18)
    gemm_mfma<256, 128, 8, 8, 8>
        <<<dim3(64, 2, 8), 256, 0, stream>>>(Eg, Bg2, part);
    reduce_pe_pack<128, 8, 8><<<2048, 256, 0, stream>>>(part, Eg, 8);

    // L3: CIN=128 COUT=64 16x16, SK=4 (1024 blocks, CPB=18)
    gemm_mfma<128, 64, 16, 16, 4>
        <<<dim3(256, 1, 4), 256, 0, stream>>>(Eg, Bg3, part);
    reduce_p<64, 16, 16><<<4096, 256, 0, stream>>>(part, a3, 4);

    // L4: 32 channel groups (2 ch/block, 2048 blocks) + tanh reduce
    kan_l4_v8<<<2048, 256, 0, stream>>>(a3, wl4, p4);
    reduce_tanh_l4_32<<<768, 256, 0, stream>>>(p4, (float*)d_out);
  } else {
    // round-1 proven fallback (needs ~16.3 MB), original layout
    float* hF  = wsf;
    float* a1F = hF + 131072;
    float* a2F = a1F + 262144;
    float* a3F = a2F + 524288;
    float* partOld = a3F + 1048576;
    linear_relu_only<<<512, 256, 0, stream>>>(x, lin_w, lin_b, hF);
    kan_gemm<512, 256, 4, 4, 64, 8>
        <<<dim3(16, 4, 8), 256, 0, stream>>>(hF, bw1, sw1, ss1, partOld);
    reduce_partials_old<256, 4, 4, 8><<<1024, 256, 0, stream>>>(partOld, a1F);
    kan_gemm<256, 128, 8, 8, 64, 2>
        <<<dim3(64, 2, 2), 256, 0, stream>>>(a1F, bw2, sw2, ss2, partOld);
    reduce_partials_old<128, 8, 8, 2><<<2048, 256, 0, stream>>>(partOld, a2F);
    kan_gemm<128, 64, 16, 16, 64, 1>
        <<<dim3(256, 1, 1), 256, 0, stream>>>(a2F, bw3, sw3, ss3, a3F);
    kan_l4_split<<<1024, 256, 0, stream>>>(a3F, bw4, sw4, ss4, partOld);
    reduce_tanh_l4<<<768, 256, 0, stream>>>(partOld, (float*)d_out);
  }
}

// Round 23
// 318.546 us; speedup vs baseline: 1.1060x; 1.1060x over previous
//
#include <hip/hip_runtime.h>
#include <cstdint>
#include <cmath>

#define BATCH 64

typedef __attribute__((ext_vector_type(8))) __bf16 bf16x8;
typedef __attribute__((ext_vector_type(16))) float f32x16;

// ---------------------------------------------------------------------------
// Spline + silu expansion: x -> [silu(x), B_0(x) .. B_7(x)]
// ---------------------------------------------------------------------------
__device__ __forceinline__ void expand9(float x, float* e) {
  float t = __expf(-x);
  e[0] = __fdividef(x, 1.f + t);  // silu
  float b[11];
#pragma unroll
  for (int j = 0; j < 11; ++j) {
    float gj  = 0.4f * (float)j - 2.2f;
    float gj1 = 0.4f * (float)(j + 1) - 2.2f;
    b[j] = (x >= gj && x < gj1) ? 1.f : 0.f;
  }
#pragma unroll
  for (int k = 1; k <= 3; ++k) {
    float inv = 1.f / (0.4f * (float)k);
#pragma unroll
    for (int j = 0; j < 11 - k; ++j) {
      float gj   = 0.4f * (float)j - 2.2f;
      float gjk1 = 0.4f * (float)(j + k + 1) - 2.2f;
      b[j] = ((x - gj) * b[j] + (gjk1 - x) * b[j + 1]) * inv;
    }
  }
#pragma unroll
  for (int v = 0; v < 8; ++v) e[v + 1] = b[v];
}

// bf16 helper (round-to-nearest-even)
__device__ __forceinline__ unsigned short f2bf(float x) {
  uint32_t u = __float_as_uint(x);
  uint32_t r = u + 0x7fffu + ((u >> 16) & 1u);
  return (unsigned short)(r >> 16);
}

// Pack 9 bf16 values into 5 dwords (pairs): d[i] = bf[2i] | bf[2i+1]<<16.
__device__ __forceinline__ void pack9(const float* e, uint32_t* d) {
  d[0] = (uint32_t)f2bf(e[0]) | ((uint32_t)f2bf(e[1]) << 16);
  d[1] = (uint32_t)f2bf(e[2]) | ((uint32_t)f2bf(e[3]) << 16);
  d[2] = (uint32_t)f2bf(e[4]) | ((uint32_t)f2bf(e[5]) << 16);
  d[3] = (uint32_t)f2bf(e[6]) | ((uint32_t)f2bf(e[7]) << 16);
  d[4] = (uint32_t)f2bf(e[8]);
}

// ---------------------------------------------------------------------------
// Prep bodies (identical math to round 22; E format = 8 dwords/pixel hi-only)
// ---------------------------------------------------------------------------
template <int F, int N>
__device__ __forceinline__ void bpack_body(int bid, const float* __restrict__ bw,
                                           const float* __restrict__ sw,
                                           const float* __restrict__ ss,
                                           unsigned short* __restrict__ Bg) {
  int idx = bid * 256 + threadIdx.x;
  int fl = idx & 15;
  int n = (idx >> 4) & (N - 1);
  int rest = idx >> 4;
  rest /= N;
  int v = rest % 9;
  int kc = rest / 9;
  int f = kc * 16 + fl;
  size_t src = (size_t)n * F + f;
  float wv = (v == 0) ? bw[src] : sw[src * 8 + (v - 1)] * ss[src];
  Bg[((size_t)kc * 9 + v) * N * 16 + (size_t)n * 16 + fl] = f2bf(wv);
}

__device__ __forceinline__ void wnl4_body(int bid, const float* __restrict__ bw,
                                          const float* __restrict__ sw,
                                          const float* __restrict__ ss,
                                          float* __restrict__ Wn) {
  int idx = bid * 256 + threadIdx.x;  // 27648 exactly
  if (idx >= 27648) return;
  int u = idx % 27;
  int o = u % 3, v = u / 3;
  int rest = idx / 27;
  int nb = rest & 3;
  rest >>= 2;
  int pc = rest & 3;
  rest >>= 2;
  int c = rest;
  int PH = pc >> 1, PW = pc & 1;
  int a = nb >> 1, b2 = nb & 1;
  float s = 0.f;
#pragma unroll
  for (int kh = 0; kh < 3; ++kh) {
    if (((kh > PH) ? 1 : 0) != a) continue;
#pragma unroll
    for (int kw = 0; kw < 3; ++kw) {
      if (((kw > PW) ? 1 : 0) != b2) continue;
      int f = c * 9 + kh * 3 + kw;
      float wv = (v == 0)
                     ? bw[o * 576 + f]
                     : sw[((size_t)(o * 576 + f)) * 8 + (v - 1)] * ss[o * 576 + f];
      s += wv;
    }
  }
  Wn[idx] = s;
}

__device__ __forceinline__ void linear_body(int bid, const float* __restrict__ x,
                                            const float* __restrict__ w,
                                            const float* __restrict__ bias,
                                            float* __restrict__ h,
                                            uint32_t* __restrict__ E) {
  int idx = bid * 256 + threadIdx.x;  // 64*2048
  int b = idx >> 11, o = idx & 2047;
  const float* xr = x + b * 100;
  const float* wr = w + o * 100;
  float acc = bias[o];
#pragma unroll 4
  for (int k = 0; k < 100; ++k) acc += xr[k] * wr[k];
  float hv = fmaxf(acc, 0.f);
  h[idx] = hv;
  float e[9];
  expand9(hv, e);
  uint32_t d[5];
  pack9(e, d);
  uint4* p = reinterpret_cast<uint4*>(E + (size_t)idx * 8);
  p[0] = make_uint4(d[0], d[1], d[2], d[3]);
  p[1] = make_uint4(d[4], 0u, 0u, 0u);
}

// One launch for ALL input-only prep: 3x bpack + wnl4 + linear.
__global__ __launch_bounds__(256) void prep_all(
    const float* __restrict__ x, const float* __restrict__ lin_w,
    const float* __restrict__ lin_b, float* __restrict__ h,
    uint32_t* __restrict__ Eg,
    const float* __restrict__ bw1, const float* __restrict__ sw1,
    const float* __restrict__ ss1, unsigned short* __restrict__ Bg1,
    const float* __restrict__ bw2, const float* __restrict__ sw2,
    const float* __restrict__ ss2, unsigned short* __restrict__ Bg2,
    const float* __restrict__ bw3, const float* __restrict__ sw3,
    const float* __restrict__ ss3, unsigned short* __restrict__ Bg3,
    const float* __restrict__ bw4, const float* __restrict__ sw4,
    const float* __restrict__ ss4, float* __restrict__ wl4) {
  int bid = blockIdx.x;
  if (bid < 41472) { bpack_body<4608, 256>(bid, bw1, sw1, ss1, Bg1); return; }
  bid -= 41472;
  if (bid < 10368) { bpack_body<2304, 128>(bid, bw2, sw2, ss2, Bg2); return; }
  bid -= 10368;
  if (bid < 2592) { bpack_body<1152, 64>(bid, bw3, sw3, ss3, Bg3); return; }
  bid -= 2592;
  if (bid < 108) { wnl4_body(bid, bw4, sw4, ss4, wl4); return; }
  bid -= 108;
  linear_body(bid, x, lin_w, lin_b, h, Eg);
}

// Standalone linear kernel (fallback path only)
__global__ __launch_bounds__(256) void linear_relu_only(
    const float* __restrict__ x, const float* __restrict__ w,
    const float* __restrict__ bias, float* __restrict__ h) {
  int idx = blockIdx.x * 256 + threadIdx.x;
  int b = idx >> 11, o = idx & 2047;
  const float* xr = x + b * 100;
  const float* wr = w + o * 100;
  float acc = bias[o];
#pragma unroll 4
  for (int k = 0; k < 100; ++k) acc += xr[k] * wr[k];
  h[idx] = fmaxf(acc, 0.f);
}

// ---------------------------------------------------------------------------
// bf16 MFMA GEMM — round-21 proven config (SK=16/8/4). Round-23 change (ONLY):
// E is hi-only 8-dword/pixel -> per tap the gather is 1 dwordx4 + 1 dword
// (20B) instead of 3 dwordx4 (48B). Per thread per chunk: 8 VMEM/80B vs
// 12 VMEM/192B. Same LDS layout; pack extracts u16 pairs from packed dwords.
// ---------------------------------------------------------------------------
template <int CIN, int COUT, int HO, int WO, int SK>
__global__ __launch_bounds__(256, 4) void gemm_mfma(
    const uint32_t* __restrict__ E, const unsigned short* __restrict__ Bg,
    float* __restrict__ part) {
  constexpr int F = CIN * 9;
  constexpr int NKC = F / 16;
  constexpr int HI = HO / 2, WI = WO / 2;
  constexpr int M = BATCH * HO * WO;
  constexpr int CPB = NKC / SK;
  static_assert(NKC % SK == 0, "sk");

  // plane 0: A-hi [9][64][16]; plane 1: B-hi
  __shared__ __align__(16) unsigned short lds[2 * 9216];

  const int t = threadIdx.x;
  const int mbase = blockIdx.x * 64;
  const int nb = blockIdx.y;
  const int kc0 = blockIdx.z * CPB;

  uint32_t ez[5];
  {
    float e0[9];
    expand9(0.f, e0);
    pack9(e0, ez);
  }

  const int lane = t & 63, wv_ = t >> 6;
  const int wm = wv_ >> 1, wn = wv_ & 1;
  const int frow = lane & 31, fkg = lane >> 5;
  const int aoff = ((wm * 32 + frow) * 16 + fkg * 8) * 2;  // bytes
  const int boff = ((wn * 32 + frow) * 16 + fkg * 8) * 2;

  // A-staging geometry: thread covers row aml, fl = flq*4..+3
  const int aml = t >> 2, flq = t & 3;
  const int am = mbase + aml;
  const int ab = am / (HO * WO), ahw = am % (HO * WO);
  const int ahh = ahw / WO, aww = ahw % WO;

  f32x16 acc;
#pragma unroll
  for (int i = 0; i < 16; ++i) acc[i] = 0.f;

  for (int ci = 0; ci < CPB; ++ci) {
    const int kc = kc0 + ci;
    __syncthreads();

    // ---- stage A (hi only): 4 taps/thread, dwordx4 + dword per tap ----
    {
      uint32_t w0[5], w1[5], w2[5], w3[5];
#define LDTAP(IDX, DST)                                                       \
  {                                                                           \
    int f = kc * 16 + flq * 4 + IDX;                                          \
    int c = f / 9, r = f - 9 * c;                                             \
    int kh = r / 3, kw = r - kh * 3;                                          \
    int hp = ahh + kh - 1, wp = aww + kw - 1;                                 \
    if ((unsigned)hp < (unsigned)HO && (unsigned)wp < (unsigned)WO) {         \
      const uint32_t* ep =                                                    \
          E + (size_t)(((ab * CIN + c) * HI + (hp >> 1)) * WI + (wp >> 1)) *  \
                  8;                                                          \
      uint4 q0 = *reinterpret_cast<const uint4*>(ep);                         \
      DST[0] = q0.x; DST[1] = q0.y; DST[2] = q0.z; DST[3] = q0.w;             \
      DST[4] = ep[4];                                                         \
    } else {                                                                  \
      _Pragma("unroll") for (int v = 0; v < 5; ++v) DST[v] = ez[v];           \
    }                                                                         \
  }
      LDTAP(0, w0)
      LDTAP(1, w1)
      LDTAP(2, w2)
      LDTAP(3, w3)
#undef LDTAP
#define GETV(W, V) (((V)&1) ? ((W)[(V) >> 1] >> 16) : ((W)[(V) >> 1] & 0xffffu))
      char* lb = reinterpret_cast<char*>(lds);
#pragma unroll
      for (int v = 0; v < 9; ++v) {
        uint32_t t0 = GETV(w0, v), t1 = GETV(w1, v);
        uint32_t t2 = GETV(w2, v), t3 = GETV(w3, v);
        uint32_t hi01 = t0 | (t1 << 16);
        uint32_t hi23 = t2 | (t3 << 16);
        *reinterpret_cast<uint2*>(lb + v * 2048 + aml * 32 + flq * 8) =
            make_uint2(hi01, hi23);
      }
#undef GETV
    }

    // ---- stage B: one plane, 1152 float4s over 256 threads ----
    {
      const unsigned short* bsrc = Bg + (size_t)kc * (9 * COUT * 16);
#define STAGEB(U)                                                             \
  {                                                                           \
    int u = (U);                                                              \
    int v = u >> 7, q = u & 127;                                              \
    int nl = q >> 1, half = q & 1;                                            \
    size_t srcE = (size_t)v * (COUT * 16) + (size_t)(nb * 64 + nl) * 16 +     \
                  half * 8;                                                   \
    int dst = 9216 + v * 1024 + nl * 16 + half * 8;                           \
    *reinterpret_cast<float4*>(&lds[dst]) =                                   \
        *reinterpret_cast<const float4*>(&bsrc[srcE]);                        \
  }
      STAGEB(t)
      STAGEB(256 + t)
      STAGEB(512 + t)
      STAGEB(768 + t)
      if (t < 128) STAGEB(1024 + t)
#undef STAGEB
    }
    __syncthreads();

    // ---- compute: 9 v-steps x 1 product ----
#pragma unroll
    for (int v = 0; v < 9; ++v) {
      const char* lbc = reinterpret_cast<const char*>(lds);
      bf16x8 ah = *reinterpret_cast<const bf16x8*>(lbc + v * 2048 + aoff);
      bf16x8 bh =
          *reinterpret_cast<const bf16x8*>(lbc + 18432 + v * 2048 + boff);
      acc = __builtin_amdgcn_mfma_f32_32x32x16_bf16(ah, bh, acc, 0, 0, 0);
    }
  }

  // ---- epilogue: C/D layout col=lane&31, row=(reg&3)+8*(reg>>2)+4*(lane>>5)
  float* p = part + (size_t)blockIdx.z * M * COUT;
  const int gn = nb * 64 + wn * 32 + frow;
#pragma unroll
  for (int r = 0; r < 16; ++r) {
    int mlocal = (r & 3) + 8 * (r >> 2) + 4 * fkg;
    int gm = mbase + wm * 32 + mlocal;
    p[(size_t)gm * COUT + gn] = acc[r];
  }
}

// ---------------------------------------------------------------------------
// Reduce split-K partials -> activation; write hi-only 8-dword expansion E.
// ---------------------------------------------------------------------------
template <int COUT, int HO, int WO>
__global__ __launch_bounds__(256) void reduce_pe_pack(
    const float* __restrict__ part, uint32_t* __restrict__ E, int SK) {
  constexpr int M = BATCH * HO * WO;
  int idx = blockIdx.x * 256 + threadIdx.x;
  int ww = idx % WO;
  int tmp = idx / WO;
  int hh = tmp % HO;
  tmp /= HO;
  int o = tmp % COUT;
  int b = tmp / COUT;
  int m = (b * HO + hh) * WO + ww;
  float s = 0.f;
  for (int k = 0; k < SK; ++k) s += part[((size_t)k * M + m) * COUT + o];
  float e[9];
  expand9(s, e);
  uint32_t d[5];
  pack9(e, d);
  uint4* p = reinterpret_cast<uint4*>(E + (size_t)idx * 8);
  p[0] = make_uint4(d[0], d[1], d[2], d[3]);
  p[1] = make_uint4(d[4], 0u, 0u, 0u);
}

template <int COUT, int HO, int WO>
__global__ __launch_bounds__(256) void reduce_p(
    const float* __restrict__ part, float* __restrict__ act, int SK) {
  constexpr int M = BATCH * HO * WO;
  int idx = blockIdx.x * 256 + threadIdx.x;
  int ww = idx % WO;
  int tmp = idx / WO;
  int hh = tmp % HO;
  tmp /= HO;
  int o = tmp % COUT;
  int b = tmp / COUT;
  int m = (b * HO + hh) * WO + ww;
  float s = 0.f;
  for (int k = 0; k < SK; ++k) s += part[((size_t)k * M + m) * COUT + o];
  act[idx] = s;
}

// ---------------------------------------------------------------------------
// L4 v8 (round-20/21 proven): 32 channel groups (2 ch/block, 2048 blocks).
// ---------------------------------------------------------------------------
template <int PH, int PW>
__device__ void l4v8_wave(const float* __restrict__ eLds,
                          const float* __restrict__ WnB,
                          const float* __restrict__ ez, int lane, int bb,
                          int cs, float* __restrict__ p4) {
  constexpr int PC = PH * 2 + PW;
  const int j = lane & 15;
  const int i0 = (lane >> 4) << 2;
#pragma unroll 1
  for (int q = 0; q < 4; ++q) {
    const int i = i0 + q;
    float acc[3] = {0.f, 0.f, 0.f};
#pragma unroll
    for (int a = 0; a < 2; ++a) {
      const int gi = i + PH - 1 + a;
      const bool vr = (unsigned)gi < 16u;
#pragma unroll
      for (int b2 = 0; b2 < 2; ++b2) {
        const int gj = j + PW - 1 + b2;
        const bool ok = vr && ((unsigned)gj < 16u);
        const int pp = ok ? (gi * 16 + gj) : 0;  // clamped safe address
        const int nbi = a * 2 + b2;
#pragma unroll
        for (int cl = 0; cl < 2; ++cl) {
          const float* ep = eLds + cl * 2304 + pp * 9;
          float en[9];
#pragma unroll
          for (int v = 0; v < 9; ++v) en[v] = ok ? ep[v] : ez[v];
          const float* wp = WnB + ((cl * 4 + PC) * 4 + nbi) * 27;
#pragma unroll
          for (int v = 0; v < 9; ++v) {
            acc[0] = fmaf(en[v], wp[v * 3 + 0], acc[0]);
            acc[1] = fmaf(en[v], wp[v * 3 + 1], acc[1]);
            acc[2] = fmaf(en[v], wp[v * 3 + 2], acc[2]);
          }
        }
      }
    }
    const int h = (i << 1) + PH, w = (j << 1) + PW;
#pragma unroll
    for (int o = 0; o < 3; ++o)
      p4[(size_t)cs * 196608 + ((bb * 3 + o) << 10) + (h << 5) + w] = acc[o];
  }
}

__global__ __launch_bounds__(256) void kan_l4_v8(
    const float* __restrict__ a3, const float* __restrict__ Wn,
    float* __restrict__ p4) {
  __shared__ float eLds[2 * 256 * 9];  // 18.4 KB
  const int bid = blockIdx.x;          // 64 bb x 32 cs
  const int bb = bid >> 5, cs = bid & 31;
  const int t = threadIdx.x;
  float ez[9];
  expand9(0.f, ez);
#pragma unroll
  for (int cl = 0; cl < 2; ++cl) {
    float x = a3[(size_t)(bb * 64 + cs * 2 + cl) * 256 + t];
    float ev[9];
    expand9(x, ev);
#pragma unroll
    for (int v = 0; v < 9; ++v) eLds[(cl * 256 + t) * 9 + v] = ev[v];
  }
  __syncthreads();
  const int wv_ = t >> 6, lane = t & 63;
  const float* WnB = Wn + (size_t)cs * 2 * (4 * 4 * 27);
  if (wv_ == 0)
    l4v8_wave<0, 0>(eLds, WnB, ez, lane, bb, cs, p4);
  else if (wv_ == 1)
    l4v8_wave<0, 1>(eLds, WnB, ez, lane, bb, cs, p4);
  else if (wv_ == 2)
    l4v8_wave<1, 0>(eLds, WnB, ez, lane, bb, cs, p4);
  else
    l4v8_wave<1, 1>(eLds, WnB, ez, lane, bb, cs, p4);
}

__global__ __launch_bounds__(256) void reduce_tanh_l4_32(
    const float* __restrict__ p4, float* __restrict__ out) {
  int i = blockIdx.x * 256 + threadIdx.x;  // 196608
  float s = 0.f;
#pragma unroll
  for (int k = 0; k < 32; ++k) s += p4[(size_t)k * 196608 + i];
  out[i] = tanhf(s);
}

__global__ __launch_bounds__(256) void reduce_tanh_l4(
    const float* __restrict__ p4, float* __restrict__ out) {
  int i = blockIdx.x * 256 + threadIdx.x;
  float s = p4[i] + p4[i + 196608] + p4[i + 2 * 196608] + p4[i + 3 * 196608];
  out[i] = tanhf(s);
}

// ---------------------------------------------------------------------------
// Fallback path (round-1 proven) for small workspace
// ---------------------------------------------------------------------------
template <int CIN, int COUT, int HO, int WO, int BN, int SK>
__global__ __launch_bounds__(256) void kan_gemm(
    const float* __restrict__ in, const float* __restrict__ bw,
    const float* __restrict__ sw, const float* __restrict__ ss,
    float* __restrict__ outp) {
  constexpr int BM = 64, TM = 4, TN = 4, FC = 16;
  constexpr int F = CIN * 9;
  constexpr int HI = HO / 2, WI = WO / 2;
  constexpr int M = BATCH * HO * WO;
  constexpr int FPB = F / SK;

  __shared__ float Ae[FC * 9][BM];

  const int t = threadIdx.x;
  const int mbase = blockIdx.x * BM;
  const int obase = blockIdx.y * BN;
  const int f0 = blockIdx.z * FPB;

  const int cg = t & (BN / TN - 1);
  const int rg = t / (BN / TN);
  const int m0 = rg * TM;
  const int o0 = obase + cg * TN;

  float acc[TM][TN] = {};

  for (int fc = f0; fc < f0 + FPB; fc += FC) {
#pragma unroll
    for (int j = 0; j < BM * FC / 256; ++j) {
      int p = j * 256 + t;
      int ml = p & (BM - 1);
      int df = p >> 6;
      int f = fc + df;
      int c = f / 9;
      int r = f - c * 9;
      int kh = r / 3, kw = r - kh * 3;
      int m = mbase + ml;
      int bb = m / (HO * WO);
      int rem = m % (HO * WO);
      int hh = rem / WO, ww = rem % WO;
      int hp = hh + kh - 1, wp = ww + kw - 1;
      float val = 0.f;
      if (hp >= 0 && hp < HO && wp >= 0 && wp < WO)
        val = in[((bb * CIN + c) * HI + (hp >> 1)) * WI + (wp >> 1)];
      float e[9];
      expand9(val, e);
#pragma unroll
      for (int v = 0; v < 9; ++v) Ae[df * 9 + v][ml] = e[v];
    }
    __syncthreads();

#pragma unroll 2
    for (int df = 0; df < FC; ++df) {
      int f = fc + df;
      float wb[TN], wsv[TN][8];
#pragma unroll
      for (int tn = 0; tn < TN; ++tn) {
        int i = (o0 + tn) * F + f;
        wb[tn] = bw[i];
        float sc = ss[i];
        const float4* sp = reinterpret_cast<const float4*>(sw + (size_t)i * 8);
        float4 s0 = sp[0], s1 = sp[1];
        wsv[tn][0] = s0.x * sc; wsv[tn][1] = s0.y * sc;
        wsv[tn][2] = s0.z * sc; wsv[tn][3] = s0.w * sc;
        wsv[tn][4] = s1.x * sc; wsv[tn][5] = s1.y * sc;
        wsv[tn][6] = s1.z * sc; wsv[tn][7] = s1.w * sc;
      }
      float a[9][TM];
#pragma unroll
      for (int v = 0; v < 9; ++v) {
        float4 q = *reinterpret_cast<const float4*>(&Ae[df * 9 + v][m0]);
        a[v][0] = q.x; a[v][1] = q.y; a[v][2] = q.z; a[v][3] = q.w;
      }
#pragma unroll
      for (int tm = 0; tm < TM; ++tm)
#pragma unroll
        for (int tn = 0; tn < TN; ++tn) acc[tm][tn] += a[0][tm] * wb[tn];
#pragma unroll
      for (int v = 1; v < 9; ++v)
#pragma unroll
        for (int tm = 0; tm < TM; ++tm)
#pragma unroll
          for (int tn = 0; tn < TN; ++tn)
            acc[tm][tn] += a[v][tm] * wsv[tn][v - 1];
    }
    __syncthreads();
  }

  if constexpr (SK > 1) {
    float* p = outp + (size_t)blockIdx.z * M * COUT;
#pragma unroll
    for (int tm = 0; tm < TM; ++tm) {
      int m = mbase + m0 + tm;
#pragma unroll
      for (int tn = 0; tn < TN; ++tn)
        p[(size_t)m * COUT + (o0 + tn)] = acc[tm][tn];
    }
  } else {
#pragma unroll
    for (int tm = 0; tm < TM; ++tm) {
      int m = mbase + m0 + tm;
      int bb = m / (HO * WO);
      int rem = m % (HO * WO);
      int hh = rem / WO, ww = rem % WO;
#pragma unroll
      for (int tn = 0; tn < TN; ++tn) {
        int o = o0 + tn;
        outp[((bb * COUT + o) * HO + hh) * WO + ww] = acc[tm][tn];
      }
    }
  }
}

template <int COUT, int HO, int WO, int SK>
__global__ __launch_bounds__(256) void reduce_partials_old(
    const float* __restrict__ part, float* __restrict__ act) {
  constexpr int M = BATCH * HO * WO;
  int idx = blockIdx.x * 256 + threadIdx.x;
  if (idx >= M * COUT) return;
  float s = 0.f;
#pragma unroll
  for (int k = 0; k < SK; ++k) s += part[(size_t)k * M * COUT + idx];
  int m = idx / COUT, o = idx - (idx / COUT) * COUT;
  int bb = m / (HO * WO);
  int rem = m % (HO * WO);
  int hh = rem / WO, ww = rem % WO;
  act[((bb * COUT + o) * HO + hh) * WO + ww] = s;
}

__global__ __launch_bounds__(256) void kan_l4_split(
    const float* __restrict__ a3, const float* __restrict__ bw,
    const float* __restrict__ sw, const float* __restrict__ ss,
    float* __restrict__ p4) {
  int tid = blockIdx.x * 256 + threadIdx.x;
  int cs = tid >> 16, pix = tid & 65535;
  int b = pix >> 10, rem = pix & 1023, h = rem >> 5, w = rem & 31;
  float acc[3] = {0.f, 0.f, 0.f};
  for (int c = cs * 16; c < cs * 16 + 16; ++c) {
#pragma unroll
    for (int kh = 0; kh < 3; ++kh) {
#pragma unroll
      for (int kw = 0; kw < 3; ++kw) {
        int f = (c * 3 + kh) * 3 + kw;
        int hp = h + kh - 1, wp = w + kw - 1;
        float x = 0.f;
        if ((unsigned)hp < 32u && (unsigned)wp < 32u)
          x = a3[((b * 64 + c) * 16 + (hp >> 1)) * 16 + (wp >> 1)];
        float e[9];
        expand9(x, e);
#pragma unroll
        for (int o = 0; o < 3; ++o) {
          int i = o * 576 + f;
          float d = e[1] * sw[i * 8 + 0];
#pragma unroll
          for (int v = 1; v < 8; ++v) d += e[v + 1] * sw[i * 8 + v];
          acc[o] += e[0] * bw[i] + d * ss[i];
        }
      }
    }
  }
#pragma unroll
  for (int o = 0; o < 3; ++o)
    p4[cs * 196608 + ((b * 3 + o) << 10) + (h << 5) + w] = acc[o];
}

// ---------------------------------------------------------------------------
extern "C" void kernel_launch(void* const* d_in, const int* in_sizes, int n_in,
                              void* d_out, int out_size, void* d_ws,
                              size_t ws_size, hipStream_t stream) {
  const float* x     = (const float*)d_in[0];
  const float* lin_w = (const float*)d_in[1];
  const float* lin_b = (const float*)d_in[2];
  const float* bw1 = (const float*)d_in[3];
  const float* sw1 = (const float*)d_in[4];
  const float* ss1 = (const float*)d_in[5];
  const float* bw2 = (const float*)d_in[6];
  const float* sw2 = (const float*)d_in[7];
  const float* ss2 = (const float*)d_in[8];
  const float* bw3 = (const float*)d_in[9];
  const float* sw3 = (const float*)d_in[10];
  const float* ss3 = (const float*)d_in[11];
  const float* bw4 = (const float*)d_in[12];
  const float* sw4 = (const float*)d_in[13];
  const float* ss4 = (const float*)d_in[14];

  float* wsf = (float*)d_ws;
  // ---- main-path layout (round 23): 16,563,200 floats = 66.3 MB ----
  float* h    = wsf;                                        // 131072
  float* a3   = wsf + 131072;                               // 1048576
  unsigned short* Bg1 = (unsigned short*)(wsf + 1179648);   // 5,308,416 floats
  unsigned short* Bg2 = (unsigned short*)(wsf + 6488064);   // 1,327,104 floats
  unsigned short* Bg3 = (unsigned short*)(wsf + 7815168);   //   331,776 floats
  float* wl4  = wsf + 8146944;                              //    27,648
  float* part = wsf + 8174592;                              // 4,194,304 (SK=16)
  uint32_t* Eg = (uint32_t*)(wsf + 12368896);               // 4,194,304 (8/pix)
  float* p4   = wsf + 8174592;  // aliases part+Eg (dead post-L3), 6.29M floats

  const size_t mainNeed = 16563200ull;

  if (ws_size / 4 >= mainNeed) {
    // One launch for all input-only prep: 3x bpack + wnl4 + linear+expand.
    prep_all<<<55052, 256, 0, stream>>>(
        x, lin_w, lin_b, h, Eg,
        bw1, sw1, ss1, Bg1,
        bw2, sw2, ss2, Bg2,
        bw3, sw3, ss3, Bg3,
        bw4, sw4, ss4, wl4);

    // L1: CIN=512 COUT=256 4x4, SK=16 (1024 blocks, CPB=18)
    gemm_mfma<512, 256, 4, 4, 16>
        <<<dim3(16, 4, 16), 256, 0, stream>>>(Eg, Bg1, part);
    reduce_pe_pack<256, 4, 4><<<1024, 256, 0, stream>>>(part, Eg, 16);

    // L2: CIN=256 COUT=128 8x8, SK=8 (1024 blocks, CPB=18)
    gemm_mfma<256, 128, 8, 8, 8>
        <<<dim3(64, 2, 8), 256, 0, stream>>>(Eg, Bg2, part);
    reduce_pe_pack<128, 8, 8><<<2048, 256, 0, stream>>>(part, Eg, 8);

    // L3: CIN=128 COUT=64 16x16, SK=4 (1024 blocks, CPB=18)
    gemm_mfma<128, 64, 16, 16, 4>
        <<<dim3(256, 1, 4), 256, 0, stream>>>(Eg, Bg3, part);
    reduce_p<64, 16, 16><<<4096, 256, 0, stream>>>(part, a3, 4);

    // L4: 32 channel groups (2 ch/block, 2048 blocks) + tanh reduce
    kan_l4_v8<<<2048, 256, 0, stream>>>(a3, wl4, p4);
    reduce_tanh_l4_32<<<768, 256, 0, stream>>>(p4, (float*)d_out);
  } else {
    // round-1 proven fallback (needs ~16.3 MB), original layout
    float* hF  = wsf;
    float* a1F = hF + 131072;
    float* a2F = a1F + 262144;
    float* a3F = a2F + 524288;
    float* partOld = a3F + 1048576;
    linear_relu_only<<<512, 256, 0, stream>>>(x, lin_w, lin_b, hF);
    kan_gemm<512, 256, 4, 4, 64, 8>
        <<<dim3(16, 4, 8), 256, 0, stream>>>(hF, bw1, sw1, ss1, partOld);
    reduce_partials_old<256, 4, 4, 8><<<1024, 256, 0, stream>>>(partOld, a1F);
    kan_gemm<256, 128, 8, 8, 64, 2>
        <<<dim3(64, 2, 2), 256, 0, stream>>>(a1F, bw2, sw2, ss2, partOld);
    reduce_partials_old<128, 8, 8, 2><<<2048, 256, 0, stream>>>(partOld, a2F);
    kan_gemm<128, 64, 16, 16, 64, 1>
        <<<dim3(256, 1, 1), 256, 0, stream>>>(a2F, bw3, sw3, ss3, a3F);
    kan_l4_split<<<1024, 256, 0, stream>>>(a3F, bw4, sw4, ss4, partOld);
    reduce_tanh_l4<<<768, 256, 0, stream>>>(partOld, (float*)d_out);
  }
}

// Round 24
// 287.802 us; speedup vs baseline: 1.2242x; 1.1068x over previous
//
#include <hip/hip_runtime.h>
#include <cstdint>
#include <cmath>

#define BATCH 64

typedef __attribute__((ext_vector_type(8))) __bf16 bf16x8;
typedef __attribute__((ext_vector_type(16))) float f32x16;

// ---------------------------------------------------------------------------
// Spline + silu expansion: x -> [silu(x), B_0(x) .. B_7(x)]
// ---------------------------------------------------------------------------
__device__ __forceinline__ void expand9(float x, float* e) {
  float t = __expf(-x);
  e[0] = __fdividef(x, 1.f + t);  // silu
  float b[11];
#pragma unroll
  for (int j = 0; j < 11; ++j) {
    float gj  = 0.4f * (float)j - 2.2f;
    float gj1 = 0.4f * (float)(j + 1) - 2.2f;
    b[j] = (x >= gj && x < gj1) ? 1.f : 0.f;
  }
#pragma unroll
  for (int k = 1; k <= 3; ++k) {
    float inv = 1.f / (0.4f * (float)k);
#pragma unroll
    for (int j = 0; j < 11 - k; ++j) {
      float gj   = 0.4f * (float)j - 2.2f;
      float gjk1 = 0.4f * (float)(j + k + 1) - 2.2f;
      b[j] = ((x - gj) * b[j] + (gjk1 - x) * b[j + 1]) * inv;
    }
  }
#pragma unroll
  for (int v = 0; v < 8; ++v) e[v + 1] = b[v];
}

// bf16 helper (round-to-nearest-even)
__device__ __forceinline__ unsigned short f2bf(float x) {
  uint32_t u = __float_as_uint(x);
  uint32_t r = u + 0x7fffu + ((u >> 16) & 1u);
  return (unsigned short)(r >> 16);
}

// Pack 9 bf16 values into 5 dwords (pairs): d[i] = bf[2i] | bf[2i+1]<<16.
__device__ __forceinline__ void pack9(const float* e, uint32_t* d) {
  d[0] = (uint32_t)f2bf(e[0]) | ((uint32_t)f2bf(e[1]) << 16);
  d[1] = (uint32_t)f2bf(e[2]) | ((uint32_t)f2bf(e[3]) << 16);
  d[2] = (uint32_t)f2bf(e[4]) | ((uint32_t)f2bf(e[5]) << 16);
  d[3] = (uint32_t)f2bf(e[6]) | ((uint32_t)f2bf(e[7]) << 16);
  d[4] = (uint32_t)f2bf(e[8]);
}

// ---------------------------------------------------------------------------
// Prep bodies. Round-24 bpack: thread per (n,f) — reads bw/ss scalars + sw
// as 2 dwordx4 (all 32B used), writes 9 wave-coalesced ushorts (stride N*16,
// contiguous across fl within each v-plane). 9x fewer threads, 8x read eff.
// ---------------------------------------------------------------------------
template <int F, int N, int LOGN>
__device__ __forceinline__ void bpack_body(int bid, const float* __restrict__ bw,
                                           const float* __restrict__ sw,
                                           const float* __restrict__ ss,
                                           unsigned short* __restrict__ Bg) {
  int idx = bid * 256 + threadIdx.x;  // over F*N
  int fl = idx & 15;
  int n = (idx >> 4) & (N - 1);
  int kc = idx >> (4 + LOGN);
  int f = kc * 16 + fl;
  size_t src = (size_t)n * F + f;
  float bv = bw[src];
  float sc = ss[src];
  const float4* sp = reinterpret_cast<const float4*>(sw + src * 8);
  float4 s0 = sp[0], s1 = sp[1];
  size_t base = ((size_t)(kc * 9) * N + n) * 16 + fl;
  const size_t vs = (size_t)N * 16;
  Bg[base]          = f2bf(bv);
  Bg[base + vs]     = f2bf(s0.x * sc);
  Bg[base + 2 * vs] = f2bf(s0.y * sc);
  Bg[base + 3 * vs] = f2bf(s0.z * sc);
  Bg[base + 4 * vs] = f2bf(s0.w * sc);
  Bg[base + 5 * vs] = f2bf(s1.x * sc);
  Bg[base + 6 * vs] = f2bf(s1.y * sc);
  Bg[base + 7 * vs] = f2bf(s1.z * sc);
  Bg[base + 8 * vs] = f2bf(s1.w * sc);
}

__device__ __forceinline__ void wnl4_body(int bid, const float* __restrict__ bw,
                                          const float* __restrict__ sw,
                                          const float* __restrict__ ss,
                                          float* __restrict__ Wn) {
  int idx = bid * 256 + threadIdx.x;  // 27648 exactly
  if (idx >= 27648) return;
  int u = idx % 27;
  int o = u % 3, v = u / 3;
  int rest = idx / 27;
  int nb = rest & 3;
  rest >>= 2;
  int pc = rest & 3;
  rest >>= 2;
  int c = rest;
  int PH = pc >> 1, PW = pc & 1;
  int a = nb >> 1, b2 = nb & 1;
  float s = 0.f;
#pragma unroll
  for (int kh = 0; kh < 3; ++kh) {
    if (((kh > PH) ? 1 : 0) != a) continue;
#pragma unroll
    for (int kw = 0; kw < 3; ++kw) {
      if (((kw > PW) ? 1 : 0) != b2) continue;
      int f = c * 9 + kh * 3 + kw;
      float wv = (v == 0)
                     ? bw[o * 576 + f]
                     : sw[((size_t)(o * 576 + f)) * 8 + (v - 1)] * ss[o * 576 + f];
      s += wv;
    }
  }
  Wn[idx] = s;
}

__device__ __forceinline__ void linear_body(int bid, const float* __restrict__ x,
                                            const float* __restrict__ w,
                                            const float* __restrict__ bias,
                                            float* __restrict__ h,
                                            uint32_t* __restrict__ E) {
  int idx = bid * 256 + threadIdx.x;  // 64*2048
  int b = idx >> 11, o = idx & 2047;
  const float* xr = x + b * 100;
  const float* wr = w + o * 100;
  float acc = bias[o];
#pragma unroll 4
  for (int k = 0; k < 100; ++k) acc += xr[k] * wr[k];
  float hv = fmaxf(acc, 0.f);
  h[idx] = hv;
  float e[9];
  expand9(hv, e);
  uint32_t d[5];
  pack9(e, d);
  uint4* p = reinterpret_cast<uint4*>(E + (size_t)idx * 8);
  p[0] = make_uint4(d[0], d[1], d[2], d[3]);
  p[1] = make_uint4(d[4], 0u, 0u, 0u);
}

// One launch for ALL input-only prep: 3x bpack + wnl4 + linear.
// Grids: 4608 + 1152 + 288 + 108 + 512 = 6668 blocks.
__global__ __launch_bounds__(256) void prep_all(
    const float* __restrict__ x, const float* __restrict__ lin_w,
    const float* __restrict__ lin_b, float* __restrict__ h,
    uint32_t* __restrict__ Eg,
    const float* __restrict__ bw1, const float* __restrict__ sw1,
    const float* __restrict__ ss1, unsigned short* __restrict__ Bg1,
    const float* __restrict__ bw2, const float* __restrict__ sw2,
    const float* __restrict__ ss2, unsigned short* __restrict__ Bg2,
    const float* __restrict__ bw3, const float* __restrict__ sw3,
    const float* __restrict__ ss3, unsigned short* __restrict__ Bg3,
    const float* __restrict__ bw4, const float* __restrict__ sw4,
    const float* __restrict__ ss4, float* __restrict__ wl4) {
  int bid = blockIdx.x;
  if (bid < 4608) { bpack_body<4608, 256, 8>(bid, bw1, sw1, ss1, Bg1); return; }
  bid -= 4608;
  if (bid < 1152) { bpack_body<2304, 128, 7>(bid, bw2, sw2, ss2, Bg2); return; }
  bid -= 1152;
  if (bid < 288) { bpack_body<1152, 64, 6>(bid, bw3, sw3, ss3, Bg3); return; }
  bid -= 288;
  if (bid < 108) { wnl4_body(bid, bw4, sw4, ss4, wl4); return; }
  bid -= 108;
  linear_body(bid, x, lin_w, lin_b, h, Eg);
}

// Standalone linear kernel (fallback path only)
__global__ __launch_bounds__(256) void linear_relu_only(
    const float* __restrict__ x, const float* __restrict__ w,
    const float* __restrict__ bias, float* __restrict__ h) {
  int idx = blockIdx.x * 256 + threadIdx.x;
  int b = idx >> 11, o = idx & 2047;
  const float* xr = x + b * 100;
  const float* wr = w + o * 100;
  float acc = bias[o];
#pragma unroll 4
  for (int k = 0; k < 100; ++k) acc += xr[k] * wr[k];
  h[idx] = fmaxf(acc, 0.f);
}

// ---------------------------------------------------------------------------
// bf16 MFMA GEMM — round-23 proven (SK=16/8/4, hi-only 8-dword E gather).
// ---------------------------------------------------------------------------
template <int CIN, int COUT, int HO, int WO, int SK>
__global__ __launch_bounds__(256, 4) void gemm_mfma(
    const uint32_t* __restrict__ E, const unsigned short* __restrict__ Bg,
    float* __restrict__ part) {
  constexpr int F = CIN * 9;
  constexpr int NKC = F / 16;
  constexpr int HI = HO / 2, WI = WO / 2;
  constexpr int M = BATCH * HO * WO;
  constexpr int CPB = NKC / SK;
  static_assert(NKC % SK == 0, "sk");

  // plane 0: A-hi [9][64][16]; plane 1: B-hi
  __shared__ __align__(16) unsigned short lds[2 * 9216];

  const int t = threadIdx.x;
  const int mbase = blockIdx.x * 64;
  const int nb = blockIdx.y;
  const int kc0 = blockIdx.z * CPB;

  uint32_t ez[5];
  {
    float e0[9];
    expand9(0.f, e0);
    pack9(e0, ez);
  }

  const int lane = t & 63, wv_ = t >> 6;
  const int wm = wv_ >> 1, wn = wv_ & 1;
  const int frow = lane & 31, fkg = lane >> 5;
  const int aoff = ((wm * 32 + frow) * 16 + fkg * 8) * 2;  // bytes
  const int boff = ((wn * 32 + frow) * 16 + fkg * 8) * 2;

  // A-staging geometry: thread covers row aml, fl = flq*4..+3
  const int aml = t >> 2, flq = t & 3;
  const int am = mbase + aml;
  const int ab = am / (HO * WO), ahw = am % (HO * WO);
  const int ahh = ahw / WO, aww = ahw % WO;

  f32x16 acc;
#pragma unroll
  for (int i = 0; i < 16; ++i) acc[i] = 0.f;

  for (int ci = 0; ci < CPB; ++ci) {
    const int kc = kc0 + ci;
    __syncthreads();

    // ---- stage A (hi only): 4 taps/thread, dwordx4 + dword per tap ----
    {
      uint32_t w0[5], w1[5], w2[5], w3[5];
#define LDTAP(IDX, DST)                                                       \
  {                                                                           \
    int f = kc * 16 + flq * 4 + IDX;                                          \
    int c = f / 9, r = f - 9 * c;                                             \
    int kh = r / 3, kw = r - kh * 3;                                          \
    int hp = ahh + kh - 1, wp = aww + kw - 1;                                 \
    if ((unsigned)hp < (unsigned)HO && (unsigned)wp < (unsigned)WO) {         \
      const uint32_t* ep =                                                    \
          E + (size_t)(((ab * CIN + c) * HI + (hp >> 1)) * WI + (wp >> 1)) *  \
                  8;                                                          \
      uint4 q0 = *reinterpret_cast<const uint4*>(ep);                         \
      DST[0] = q0.x; DST[1] = q0.y; DST[2] = q0.z; DST[3] = q0.w;             \
      DST[4] = ep[4];                                                         \
    } else {                                                                  \
      _Pragma("unroll") for (int v = 0; v < 5; ++v) DST[v] = ez[v];           \
    }                                                                         \
  }
      LDTAP(0, w0)
      LDTAP(1, w1)
      LDTAP(2, w2)
      LDTAP(3, w3)
#undef LDTAP
#define GETV(W, V) (((V)&1) ? ((W)[(V) >> 1] >> 16) : ((W)[(V) >> 1] & 0xffffu))
      char* lb = reinterpret_cast<char*>(lds);
#pragma unroll
      for (int v = 0; v < 9; ++v) {
        uint32_t t0 = GETV(w0, v), t1 = GETV(w1, v);
        uint32_t t2 = GETV(w2, v), t3 = GETV(w3, v);
        uint32_t hi01 = t0 | (t1 << 16);
        uint32_t hi23 = t2 | (t3 << 16);
        *reinterpret_cast<uint2*>(lb + v * 2048 + aml * 32 + flq * 8) =
            make_uint2(hi01, hi23);
      }
#undef GETV
    }

    // ---- stage B: one plane, 1152 float4s over 256 threads ----
    {
      const unsigned short* bsrc = Bg + (size_t)kc * (9 * COUT * 16);
#define STAGEB(U)                                                             \
  {                                                                           \
    int u = (U);                                                              \
    int v = u >> 7, q = u & 127;                                              \
    int nl = q >> 1, half = q & 1;                                            \
    size_t srcE = (size_t)v * (COUT * 16) + (size_t)(nb * 64 + nl) * 16 +     \
                  half * 8;                                                   \
    int dst = 9216 + v * 1024 + nl * 16 + half * 8;                           \
    *reinterpret_cast<float4*>(&lds[dst]) =                                   \
        *reinterpret_cast<const float4*>(&bsrc[srcE]);                        \
  }
      STAGEB(t)
      STAGEB(256 + t)
      STAGEB(512 + t)
      STAGEB(768 + t)
      if (t < 128) STAGEB(1024 + t)
#undef STAGEB
    }
    __syncthreads();

    // ---- compute: 9 v-steps x 1 product ----
#pragma unroll
    for (int v = 0; v < 9; ++v) {
      const char* lbc = reinterpret_cast<const char*>(lds);
      bf16x8 ah = *reinterpret_cast<const bf16x8*>(lbc + v * 2048 + aoff);
      bf16x8 bh =
          *reinterpret_cast<const bf16x8*>(lbc + 18432 + v * 2048 + boff);
      acc = __builtin_amdgcn_mfma_f32_32x32x16_bf16(ah, bh, acc, 0, 0, 0);
    }
  }

  // ---- epilogue: C/D layout col=lane&31, row=(reg&3)+8*(reg>>2)+4*(lane>>5)
  float* p = part + (size_t)blockIdx.z * M * COUT;
  const int gn = nb * 64 + wn * 32 + frow;
#pragma unroll
  for (int r = 0; r < 16; ++r) {
    int mlocal = (r & 3) + 8 * (r >> 2) + 4 * fkg;
    int gm = mbase + wm * 32 + mlocal;
    p[(size_t)gm * COUT + gn] = acc[r];
  }
}

// ---------------------------------------------------------------------------
// Reduce split-K partials -> activation; write hi-only 8-dword expansion E.
// ---------------------------------------------------------------------------
template <int COUT, int HO, int WO>
__global__ __launch_bounds__(256) void reduce_pe_pack(
    const float* __restrict__ part, uint32_t* __restrict__ E, int SK) {
  constexpr int M = BATCH * HO * WO;
  int idx = blockIdx.x * 256 + threadIdx.x;
  int ww = idx % WO;
  int tmp = idx / WO;
  int hh = tmp % HO;
  tmp /= HO;
  int o = tmp % COUT;
  int b = tmp / COUT;
  int m = (b * HO + hh) * WO + ww;
  float s = 0.f;
  for (int k = 0; k < SK; ++k) s += part[((size_t)k * M + m) * COUT + o];
  float e[9];
  expand9(s, e);
  uint32_t d[5];
  pack9(e, d);
  uint4* p = reinterpret_cast<uint4*>(E + (size_t)idx * 8);
  p[0] = make_uint4(d[0], d[1], d[2], d[3]);
  p[1] = make_uint4(d[4], 0u, 0u, 0u);
}

template <int COUT, int HO, int WO>
__global__ __launch_bounds__(256) void reduce_p(
    const float* __restrict__ part, float* __restrict__ act, int SK) {
  constexpr int M = BATCH * HO * WO;
  int idx = blockIdx.x * 256 + threadIdx.x;
  int ww = idx % WO;
  int tmp = idx / WO;
  int hh = tmp % HO;
  tmp /= HO;
  int o = tmp % COUT;
  int b = tmp / COUT;
  int m = (b * HO + hh) * WO + ww;
  float s = 0.f;
  for (int k = 0; k < SK; ++k) s += part[((size_t)k * M + m) * COUT + o];
  act[idx] = s;
}

// ---------------------------------------------------------------------------
// L4 v8 (round-20/21 proven): 32 channel groups (2 ch/block, 2048 blocks).
// ---------------------------------------------------------------------------
template <int PH, int PW>
__device__ void l4v8_wave(const float* __restrict__ eLds,
                          const float* __restrict__ WnB,
                          const float* __restrict__ ez, int lane, int bb,
                          int cs, float* __restrict__ p4) {
  constexpr int PC = PH * 2 + PW;
  const int j = lane & 15;
  const int i0 = (lane >> 4) << 2;
#pragma unroll 1
  for (int q = 0; q < 4; ++q) {
    const int i = i0 + q;
    float acc[3] = {0.f, 0.f, 0.f};
#pragma unroll
    for (int a = 0; a < 2; ++a) {
      const int gi = i + PH - 1 + a;
      const bool vr = (unsigned)gi < 16u;
#pragma unroll
      for (int b2 = 0; b2 < 2; ++b2) {
        const int gj = j + PW - 1 + b2;
        const bool ok = vr && ((unsigned)gj < 16u);
        const int pp = ok ? (gi * 16 + gj) : 0;  // clamped safe address
        const int nbi = a * 2 + b2;
#pragma unroll
        for (int cl = 0; cl < 2; ++cl) {
          const float* ep = eLds + cl * 2304 + pp * 9;
          float en[9];
#pragma unroll
          for (int v = 0; v < 9; ++v) en[v] = ok ? ep[v] : ez[v];
          const float* wp = WnB + ((cl * 4 + PC) * 4 + nbi) * 27;
#pragma unroll
          for (int v = 0; v < 9; ++v) {
            acc[0] = fmaf(en[v], wp[v * 3 + 0], acc[0]);
            acc[1] = fmaf(en[v], wp[v * 3 + 1], acc[1]);
            acc[2] = fmaf(en[v], wp[v * 3 + 2], acc[2]);
          }
        }
      }
    }
    const int h = (i << 1) + PH, w = (j << 1) + PW;
#pragma unroll
    for (int o = 0; o < 3; ++o)
      p4[(size_t)cs * 196608 + ((bb * 3 + o) << 10) + (h << 5) + w] = acc[o];
  }
}

__global__ __launch_bounds__(256) void kan_l4_v8(
    const float* __restrict__ a3, const float* __restrict__ Wn,
    float* __restrict__ p4) {
  __shared__ float eLds[2 * 256 * 9];  // 18.4 KB
  const int bid = blockIdx.x;          // 64 bb x 32 cs
  const int bb = bid >> 5, cs = bid & 31;
  const int t = threadIdx.x;
  float ez[9];
  expand9(0.f, ez);
#pragma unroll
  for (int cl = 0; cl < 2; ++cl) {
    float x = a3[(size_t)(bb * 64 + cs * 2 + cl) * 256 + t];
    float ev[9];
    expand9(x, ev);
#pragma unroll
    for (int v = 0; v < 9; ++v) eLds[(cl * 256 + t) * 9 + v] = ev[v];
  }
  __syncthreads();
  const int wv_ = t >> 6, lane = t & 63;
  const float* WnB = Wn + (size_t)cs * 2 * (4 * 4 * 27);
  if (wv_ == 0)
    l4v8_wave<0, 0>(eLds, WnB, ez, lane, bb, cs, p4);
  else if (wv_ == 1)
    l4v8_wave<0, 1>(eLds, WnB, ez, lane, bb, cs, p4);
  else if (wv_ == 2)
    l4v8_wave<1, 0>(eLds, WnB, ez, lane, bb, cs, p4);
  else
    l4v8_wave<1, 1>(eLds, WnB, ez, lane, bb, cs, p4);
}

__global__ __launch_bounds__(256) void reduce_tanh_l4_32(
    const float* __restrict__ p4, float* __restrict__ out) {
  int i = blockIdx.x * 256 + threadIdx.x;  // 196608
  float s = 0.f;
#pragma unroll
  for (int k = 0; k < 32; ++k) s += p4[(size_t)k * 196608 + i];
  out[i] = tanhf(s);
}

__global__ __launch_bounds__(256) void reduce_tanh_l4(
    const float* __restrict__ p4, float* __restrict__ out) {
  int i = blockIdx.x * 256 + threadIdx.x;
  float s = p4[i] + p4[i + 196608] + p4[i + 2 * 196608] + p4[i + 3 * 196608];
  out[i] = tanhf(s);
}

// ---------------------------------------------------------------------------
// Fallback path (round-1 proven) for small workspace
// ---------------------------------------------------------------------------
template <int CIN, int COUT, int HO, int WO, int BN, int SK>
__global__ __launch_bounds__(256) void kan_gemm(
    const float* __restrict__ in, const float* __restrict__ bw,
    const float* __restrict__ sw, const float* __restrict__ ss,
    float* __restrict__ outp) {
  constexpr int BM = 64, TM = 4, TN = 4, FC = 16;
  constexpr int F = CIN * 9;
  constexpr int HI = HO / 2, WI = WO / 2;
  constexpr int M = BATCH * HO * WO;
  constexpr int FPB = F / SK;

  __shared__ float Ae[FC * 9][BM];

  const int t = threadIdx.x;
  const int mbase = blockIdx.x * BM;
  const int obase = blockIdx.y * BN;
  const int f0 = blockIdx.z * FPB;

  const int cg = t & (BN / TN - 1);
  const int rg = t / (BN / TN);
  const int m0 = rg * TM;
  const int o0 = obase + cg * TN;

  float acc[TM][TN] = {};

  for (int fc = f0; fc < f0 + FPB; fc += FC) {
#pragma unroll
    for (int j = 0; j < BM * FC / 256; ++j) {
      int p = j * 256 + t;
      int ml = p & (BM - 1);
      int df = p >> 6;
      int f = fc + df;
      int c = f / 9;
      int r = f - c * 9;
      int kh = r / 3, kw = r - kh * 3;
      int m = mbase + ml;
      int bb = m / (HO * WO);
      int rem = m % (HO * WO);
      int hh = rem / WO, ww = rem % WO;
      int hp = hh + kh - 1, wp = ww + kw - 1;
      float val = 0.f;
      if (hp >= 0 && hp < HO && wp >= 0 && wp < WO)
        val = in[((bb * CIN + c) * HI + (hp >> 1)) * WI + (wp >> 1)];
      float e[9];
      expand9(val, e);
#pragma unroll
      for (int v = 0; v < 9; ++v) Ae[df * 9 + v][ml] = e[v];
    }
    __syncthreads();

#pragma unroll 2
    for (int df = 0; df < FC; ++df) {
      int f = fc + df;
      float wb[TN], wsv[TN][8];
#pragma unroll
      for (int tn = 0; tn < TN; ++tn) {
        int i = (o0 + tn) * F + f;
        wb[tn] = bw[i];
        float sc = ss[i];
        const float4* sp = reinterpret_cast<const float4*>(sw + (size_t)i * 8);
        float4 s0 = sp[0], s1 = sp[1];
        wsv[tn][0] = s0.x * sc; wsv[tn][1] = s0.y * sc;
        wsv[tn][2] = s0.z * sc; wsv[tn][3] = s0.w * sc;
        wsv[tn][4] = s1.x * sc; wsv[tn][5] = s1.y * sc;
        wsv[tn][6] = s1.z * sc; wsv[tn][7] = s1.w * sc;
      }
      float a[9][TM];
#pragma unroll
      for (int v = 0; v < 9; ++v) {
        float4 q = *reinterpret_cast<const float4*>(&Ae[df * 9 + v][m0]);
        a[v][0] = q.x; a[v][1] = q.y; a[v][2] = q.z; a[v][3] = q.w;
      }
#pragma unroll
      for (int tm = 0; tm < TM; ++tm)
#pragma unroll
        for (int tn = 0; tn < TN; ++tn) acc[tm][tn] += a[0][tm] * wb[tn];
#pragma unroll
      for (int v = 1; v < 9; ++v)
#pragma unroll
        for (int tm = 0; tm < TM; ++tm)
#pragma unroll
          for (int tn = 0; tn < TN; ++tn)
            acc[tm][tn] += a[v][tm] * wsv[tn][v - 1];
    }
    __syncthreads();
  }

  if constexpr (SK > 1) {
    float* p = outp + (size_t)blockIdx.z * M * COUT;
#pragma unroll
    for (int tm = 0; tm < TM; ++tm) {
      int m = mbase + m0 + tm;
#pragma unroll
      for (int tn = 0; tn < TN; ++tn)
        p[(size_t)m * COUT + (o0 + tn)] = acc[tm][tn];
    }
  } else {
#pragma unroll
    for (int tm = 0; tm < TM; ++tm) {
      int m = mbase + m0 + tm;
      int bb = m / (HO * WO);
      int rem = m % (HO * WO);
      int hh = rem / WO, ww = rem % WO;
#pragma unroll
      for (int tn = 0; tn < TN; ++tn) {
        int o = o0 + tn;
        outp[((bb * COUT + o) * HO + hh) * WO + ww] = acc[tm][tn];
      }
    }
  }
}

template <int COUT, int HO, int WO, int SK>
__global__ __launch_bounds__(256) void reduce_partials_old(
    const float* __restrict__ part, float* __restrict__ act) {
  constexpr int M = BATCH * HO * WO;
  int idx = blockIdx.x * 256 + threadIdx.x;
  if (idx >= M * COUT) return;
  float s = 0.f;
#pragma unroll
  for (int k = 0; k < SK; ++k) s += part[(size_t)k * M * COUT + idx];
  int m = idx / COUT, o = idx - (idx / COUT) * COUT;
  int bb = m / (HO * WO);
  int rem = m % (HO * WO);
  int hh = rem / WO, ww = rem % WO;
  act[((bb * COUT + o) * HO + hh) * WO + ww] = s;
}

__global__ __launch_bounds__(256) void kan_l4_split(
    const float* __restrict__ a3, const float* __restrict__ bw,
    const float* __restrict__ sw, const float* __restrict__ ss,
    float* __restrict__ p4) {
  int tid = blockIdx.x * 256 + threadIdx.x;
  int cs = tid >> 16, pix = tid & 65535;
  int b = pix >> 10, rem = pix & 1023, h = rem >> 5, w = rem & 31;
  float acc[3] = {0.f, 0.f, 0.f};
  for (int c = cs * 16; c < cs * 16 + 16; ++c) {
#pragma unroll
    for (int kh = 0; kh < 3; ++kh) {
#pragma unroll
      for (int kw = 0; kw < 3; ++kw) {
        int f = (c * 3 + kh) * 3 + kw;
        int hp = h + kh - 1, wp = w + kw - 1;
        float x = 0.f;
        if ((unsigned)hp < 32u && (unsigned)wp < 32u)
          x = a3[((b * 64 + c) * 16 + (hp >> 1)) * 16 + (wp >> 1)];
        float e[9];
        expand9(x, e);
#pragma unroll
        for (int o = 0; o < 3; ++o) {
          int i = o * 576 + f;
          float d = e[1] * sw[i * 8 + 0];
#pragma unroll
          for (int v = 1; v < 8; ++v) d += e[v + 1] * sw[i * 8 + v];
          acc[o] += e[0] * bw[i] + d * ss[i];
        }
      }
    }
  }
#pragma unroll
  for (int o = 0; o < 3; ++o)
    p4[cs * 196608 + ((b * 3 + o) << 10) + (h << 5) + w] = acc[o];
}

// ---------------------------------------------------------------------------
extern "C" void kernel_launch(void* const* d_in, const int* in_sizes, int n_in,
                              void* d_out, int out_size, void* d_ws,
                              size_t ws_size, hipStream_t stream) {
  const float* x     = (const float*)d_in[0];
  const float* lin_w = (const float*)d_in[1];
  const float* lin_b = (const float*)d_in[2];
  const float* bw1 = (const float*)d_in[3];
  const float* sw1 = (const float*)d_in[4];
  const float* ss1 = (const float*)d_in[5];
  const float* bw2 = (const float*)d_in[6];
  const float* sw2 = (const float*)d_in[7];
  const float* ss2 = (const float*)d_in[8];
  const float* bw3 = (const float*)d_in[9];
  const float* sw3 = (const float*)d_in[10];
  const float* ss3 = (const float*)d_in[11];
  const float* bw4 = (const float*)d_in[12];
  const float* sw4 = (const float*)d_in[13];
  const float* ss4 = (const float*)d_in[14];

  float* wsf = (float*)d_ws;
  // ---- main-path layout (round 24 = round 23): 16,563,200 floats = 66.3 MB
  float* h    = wsf;                                        // 131072
  float* a3   = wsf + 131072;                               // 1048576
  unsigned short* Bg1 = (unsigned short*)(wsf + 1179648);   // 5,308,416 floats
  unsigned short* Bg2 = (unsigned short*)(wsf + 6488064);   // 1,327,104 floats
  unsigned short* Bg3 = (unsigned short*)(wsf + 7815168);   //   331,776 floats
  float* wl4  = wsf + 8146944;                              //    27,648
  float* part = wsf + 8174592;                              // 4,194,304 (SK=16)
  uint32_t* Eg = (uint32_t*)(wsf + 12368896);               // 4,194,304 (8/pix)
  float* p4   = wsf + 8174592;  // aliases part+Eg (dead post-L3), 6.29M floats

  const size_t mainNeed = 16563200ull;

  if (ws_size / 4 >= mainNeed) {
    // One launch for all input-only prep: 3x bpack + wnl4 + linear+expand.
    prep_all<<<6668, 256, 0, stream>>>(
        x, lin_w, lin_b, h, Eg,
        bw1, sw1, ss1, Bg1,
        bw2, sw2, ss2, Bg2,
        bw3, sw3, ss3, Bg3,
        bw4, sw4, ss4, wl4);

    // L1: CIN=512 COUT=256 4x4, SK=16 (1024 blocks, CPB=18)
    gemm_mfma<512, 256, 4, 4, 16>
        <<<dim3(16, 4, 16), 256, 0, stream>>>(Eg, Bg1, part);
    reduce_pe_pack<256, 4, 4><<<1024, 256, 0, stream>>>(part, Eg, 16);

    // L2: CIN=256 COUT=128 8x8, SK=8 (1024 blocks, CPB=18)
    gemm_mfma<256, 128, 8, 8, 8>
        <<<dim3(64, 2, 8), 256, 0, stream>>>(Eg, Bg2, part);
    reduce_pe_pack<128, 8, 8><<<2048, 256, 0, stream>>>(part, Eg, 8);

    // L3: CIN=128 COUT=64 16x16, SK=4 (1024 blocks, CPB=18)
    gemm_mfma<128, 64, 16, 16, 4>
        <<<dim3(256, 1, 4), 256, 0, stream>>>(Eg, Bg3, part);
    reduce_p<64, 16, 16><<<4096, 256, 0, stream>>>(part, a3, 4);

    // L4: 32 channel groups (2 ch/block, 2048 blocks) + tanh reduce
    kan_l4_v8<<<2048, 256, 0, stream>>>(a3, wl4, p4);
    reduce_tanh_l4_32<<<768, 256, 0, stream>>>(p4, (float*)d_out);
  } else {
    // round-1 proven fallback (needs ~16.3 MB), original layout
    float* hF  = wsf;
    float* a1F = hF + 131072;
    float* a2F = a1F + 262144;
    float* a3F = a2F + 524288;
    float* partOld = a3F + 1048576;
    linear_relu_only<<<512, 256, 0, stream>>>(x, lin_w, lin_b, hF);
    kan_gemm<512, 256, 4, 4, 64, 8>
        <<<dim3(16, 4, 8), 256, 0, stream>>>(hF, bw1, sw1, ss1, partOld);
    reduce_partials_old<256, 4, 4, 8><<<1024, 256, 0, stream>>>(partOld, a1F);
    kan_gemm<256, 128, 8, 8, 64, 2>
        <<<dim3(64, 2, 2), 256, 0, stream>>>(a1F, bw2, sw2, ss2, partOld);
    reduce_partials_old<128, 8, 8, 2><<<2048, 256, 0, stream>>>(partOld, a2F);
    kan_gemm<128, 64, 16, 16, 64, 1>
        <<<dim3(256, 1, 1), 256, 0, stream>>>(a2F, bw3, sw3, ss3, a3F);
    kan_l4_split<<<1024, 256, 0, stream>>>(a3F, bw4, sw4, ss4, partOld);
    reduce_tanh_l4<<<768, 256, 0, stream>>>(partOld, (float*)d_out);
  }
}

// Round 25
// 258.706 us; speedup vs baseline: 1.3619x; 1.1125x over previous
//
#include <hip/hip_runtime.h>
#include <cstdint>
#include <cmath>

#define BATCH 64

typedef __attribute__((ext_vector_type(8))) __bf16 bf16x8;
typedef __attribute__((ext_vector_type(16))) float f32x16;

// ---------------------------------------------------------------------------
// Spline + silu expansion: x -> [silu(x), B_0(x) .. B_7(x)]
// ---------------------------------------------------------------------------
__device__ __forceinline__ void expand9(float x, float* e) {
  float t = __expf(-x);
  e[0] = __fdividef(x, 1.f + t);  // silu
  float b[11];
#pragma unroll
  for (int j = 0; j < 11; ++j) {
    float gj  = 0.4f * (float)j - 2.2f;
    float gj1 = 0.4f * (float)(j + 1) - 2.2f;
    b[j] = (x >= gj && x < gj1) ? 1.f : 0.f;
  }
#pragma unroll
  for (int k = 1; k <= 3; ++k) {
    float inv = 1.f / (0.4f * (float)k);
#pragma unroll
    for (int j = 0; j < 11 - k; ++j) {
      float gj   = 0.4f * (float)j - 2.2f;
      float gjk1 = 0.4f * (float)(j + k + 1) - 2.2f;
      b[j] = ((x - gj) * b[j] + (gjk1 - x) * b[j + 1]) * inv;
    }
  }
#pragma unroll
  for (int v = 0; v < 8; ++v) e[v + 1] = b[v];
}

// bf16 helper (round-to-nearest-even)
__device__ __forceinline__ unsigned short f2bf(float x) {
  uint32_t u = __float_as_uint(x);
  uint32_t r = u + 0x7fffu + ((u >> 16) & 1u);
  return (unsigned short)(r >> 16);
}

// Pack 9 bf16 values into 5 dwords (pairs): d[i] = bf[2i] | bf[2i+1]<<16.
__device__ __forceinline__ void pack9(const float* e, uint32_t* d) {
  d[0] = (uint32_t)f2bf(e[0]) | ((uint32_t)f2bf(e[1]) << 16);
  d[1] = (uint32_t)f2bf(e[2]) | ((uint32_t)f2bf(e[3]) << 16);
  d[2] = (uint32_t)f2bf(e[4]) | ((uint32_t)f2bf(e[5]) << 16);
  d[3] = (uint32_t)f2bf(e[6]) | ((uint32_t)f2bf(e[7]) << 16);
  d[4] = (uint32_t)f2bf(e[8]);
}

// ---------------------------------------------------------------------------
// Prep bodies (round-24 proven).
// ---------------------------------------------------------------------------
template <int F, int N, int LOGN>
__device__ __forceinline__ void bpack_body(int bid, const float* __restrict__ bw,
                                           const float* __restrict__ sw,
                                           const float* __restrict__ ss,
                                           unsigned short* __restrict__ Bg) {
  int idx = bid * 256 + threadIdx.x;  // over F*N
  int fl = idx & 15;
  int n = (idx >> 4) & (N - 1);
  int kc = idx >> (4 + LOGN);
  int f = kc * 16 + fl;
  size_t src = (size_t)n * F + f;
  float bv = bw[src];
  float sc = ss[src];
  const float4* sp = reinterpret_cast<const float4*>(sw + src * 8);
  float4 s0 = sp[0], s1 = sp[1];
  size_t base = ((size_t)(kc * 9) * N + n) * 16 + fl;
  const size_t vs = (size_t)N * 16;
  Bg[base]          = f2bf(bv);
  Bg[base + vs]     = f2bf(s0.x * sc);
  Bg[base + 2 * vs] = f2bf(s0.y * sc);
  Bg[base + 3 * vs] = f2bf(s0.z * sc);
  Bg[base + 4 * vs] = f2bf(s0.w * sc);
  Bg[base + 5 * vs] = f2bf(s1.x * sc);
  Bg[base + 6 * vs] = f2bf(s1.y * sc);
  Bg[base + 7 * vs] = f2bf(s1.z * sc);
  Bg[base + 8 * vs] = f2bf(s1.w * sc);
}

__device__ __forceinline__ void wnl4_body(int bid, const float* __restrict__ bw,
                                          const float* __restrict__ sw,
                                          const float* __restrict__ ss,
                                          float* __restrict__ Wn) {
  int idx = bid * 256 + threadIdx.x;  // 27648 exactly
  if (idx >= 27648) return;
  int u = idx % 27;
  int o = u % 3, v = u / 3;
  int rest = idx / 27;
  int nb = rest & 3;
  rest >>= 2;
  int pc = rest & 3;
  rest >>= 2;
  int c = rest;
  int PH = pc >> 1, PW = pc & 1;
  int a = nb >> 1, b2 = nb & 1;
  float s = 0.f;
#pragma unroll
  for (int kh = 0; kh < 3; ++kh) {
    if (((kh > PH) ? 1 : 0) != a) continue;
#pragma unroll
    for (int kw = 0; kw < 3; ++kw) {
      if (((kw > PW) ? 1 : 0) != b2) continue;
      int f = c * 9 + kh * 3 + kw;
      float wv = (v == 0)
                     ? bw[o * 576 + f]
                     : sw[((size_t)(o * 576 + f)) * 8 + (v - 1)] * ss[o * 576 + f];
      s += wv;
    }
  }
  Wn[idx] = s;
}

__device__ __forceinline__ void linear_body(int bid, const float* __restrict__ x,
                                            const float* __restrict__ w,
                                            const float* __restrict__ bias,
                                            float* __restrict__ h,
                                            uint32_t* __restrict__ E) {
  int idx = bid * 256 + threadIdx.x;  // 64*2048
  int b = idx >> 11, o = idx & 2047;
  const float* xr = x + b * 100;
  const float* wr = w + o * 100;
  float acc = bias[o];
#pragma unroll 4
  for (int k = 0; k < 100; ++k) acc += xr[k] * wr[k];
  float hv = fmaxf(acc, 0.f);
  h[idx] = hv;
  float e[9];
  expand9(hv, e);
  uint32_t d[5];
  pack9(e, d);
  uint4* p = reinterpret_cast<uint4*>(E + (size_t)idx * 8);
  p[0] = make_uint4(d[0], d[1], d[2], d[3]);
  p[1] = make_uint4(d[4], 0u, 0u, 0u);
}

// One launch for ALL input-only prep: 3x bpack + wnl4 + linear.
__global__ __launch_bounds__(256) void prep_all(
    const float* __restrict__ x, const float* __restrict__ lin_w,
    const float* __restrict__ lin_b, float* __restrict__ h,
    uint32_t* __restrict__ Eg,
    const float* __restrict__ bw1, const float* __restrict__ sw1,
    const float* __restrict__ ss1, unsigned short* __restrict__ Bg1,
    const float* __restrict__ bw2, const float* __restrict__ sw2,
    const float* __restrict__ ss2, unsigned short* __restrict__ Bg2,
    const float* __restrict__ bw3, const float* __restrict__ sw3,
    const float* __restrict__ ss3, unsigned short* __restrict__ Bg3,
    const float* __restrict__ bw4, const float* __restrict__ sw4,
    const float* __restrict__ ss4, float* __restrict__ wl4) {
  int bid = blockIdx.x;
  if (bid < 4608) { bpack_body<4608, 256, 8>(bid, bw1, sw1, ss1, Bg1); return; }
  bid -= 4608;
  if (bid < 1152) { bpack_body<2304, 128, 7>(bid, bw2, sw2, ss2, Bg2); return; }
  bid -= 1152;
  if (bid < 288) { bpack_body<1152, 64, 6>(bid, bw3, sw3, ss3, Bg3); return; }
  bid -= 288;
  if (bid < 108) { wnl4_body(bid, bw4, sw4, ss4, wl4); return; }
  bid -= 108;
  linear_body(bid, x, lin_w, lin_b, h, Eg);
}

// Standalone linear kernel (fallback path only)
__global__ __launch_bounds__(256) void linear_relu_only(
    const float* __restrict__ x, const float* __restrict__ w,
    const float* __restrict__ bias, float* __restrict__ h) {
  int idx = blockIdx.x * 256 + threadIdx.x;
  int b = idx >> 11, o = idx & 2047;
  const float* xr = x + b * 100;
  const float* wr = w + o * 100;
  float acc = bias[o];
#pragma unroll 4
  for (int k = 0; k < 100; ++k) acc += xr[k] * wr[k];
  h[idx] = fmaxf(acc, 0.f);
}

// ---------------------------------------------------------------------------
// bf16 MFMA GEMM — round-24 proven (SK=16/8/4, hi-only 8-dword E gather).
// ---------------------------------------------------------------------------
template <int CIN, int COUT, int HO, int WO, int SK>
__global__ __launch_bounds__(256, 4) void gemm_mfma(
    const uint32_t* __restrict__ E, const unsigned short* __restrict__ Bg,
    float* __restrict__ part) {
  constexpr int F = CIN * 9;
  constexpr int NKC = F / 16;
  constexpr int HI = HO / 2, WI = WO / 2;
  constexpr int M = BATCH * HO * WO;
  constexpr int CPB = NKC / SK;
  static_assert(NKC % SK == 0, "sk");

  // plane 0: A-hi [9][64][16]; plane 1: B-hi
  __shared__ __align__(16) unsigned short lds[2 * 9216];

  const int t = threadIdx.x;
  const int mbase = blockIdx.x * 64;
  const int nb = blockIdx.y;
  const int kc0 = blockIdx.z * CPB;

  uint32_t ez[5];
  {
    float e0[9];
    expand9(0.f, e0);
    pack9(e0, ez);
  }

  const int lane = t & 63, wv_ = t >> 6;
  const int wm = wv_ >> 1, wn = wv_ & 1;
  const int frow = lane & 31, fkg = lane >> 5;
  const int aoff = ((wm * 32 + frow) * 16 + fkg * 8) * 2;  // bytes
  const int boff = ((wn * 32 + frow) * 16 + fkg * 8) * 2;

  // A-staging geometry: thread covers row aml, fl = flq*4..+3
  const int aml = t >> 2, flq = t & 3;
  const int am = mbase + aml;
  const int ab = am / (HO * WO), ahw = am % (HO * WO);
  const int ahh = ahw / WO, aww = ahw % WO;

  f32x16 acc;
#pragma unroll
  for (int i = 0; i < 16; ++i) acc[i] = 0.f;

  for (int ci = 0; ci < CPB; ++ci) {
    const int kc = kc0 + ci;
    __syncthreads();

    // ---- stage A (hi only): 4 taps/thread, dwordx4 + dword per tap ----
    {
      uint32_t w0[5], w1[5], w2[5], w3[5];
#define LDTAP(IDX, DST)                                                       \
  {                                                                           \
    int f = kc * 16 + flq * 4 + IDX;                                          \
    int c = f / 9, r = f - 9 * c;                                             \
    int kh = r / 3, kw = r - kh * 3;                                          \
    int hp = ahh + kh - 1, wp = aww + kw - 1;                                 \
    if ((unsigned)hp < (unsigned)HO && (unsigned)wp < (unsigned)WO) {         \
      const uint32_t* ep =                                                    \
          E + (size_t)(((ab * CIN + c) * HI + (hp >> 1)) * WI + (wp >> 1)) *  \
                  8;                                                          \
      uint4 q0 = *reinterpret_cast<const uint4*>(ep);                         \
      DST[0] = q0.x; DST[1] = q0.y; DST[2] = q0.z; DST[3] = q0.w;             \
      DST[4] = ep[4];                                                         \
    } else {                                                                  \
      _Pragma("unroll") for (int v = 0; v < 5; ++v) DST[v] = ez[v];           \
    }                                                                         \
  }
      LDTAP(0, w0)
      LDTAP(1, w1)
      LDTAP(2, w2)
      LDTAP(3, w3)
#undef LDTAP
#define GETV(W, V) (((V)&1) ? ((W)[(V) >> 1] >> 16) : ((W)[(V) >> 1] & 0xffffu))
      char* lb = reinterpret_cast<char*>(lds);
#pragma unroll
      for (int v = 0; v < 9; ++v) {
        uint32_t t0 = GETV(w0, v), t1 = GETV(w1, v);
        uint32_t t2 = GETV(w2, v), t3 = GETV(w3, v);
        uint32_t hi01 = t0 | (t1 << 16);
        uint32_t hi23 = t2 | (t3 << 16);
        *reinterpret_cast<uint2*>(lb + v * 2048 + aml * 32 + flq * 8) =
            make_uint2(hi01, hi23);
      }
#undef GETV
    }

    // ---- stage B: one plane, 1152 float4s over 256 threads ----
    {
      const unsigned short* bsrc = Bg + (size_t)kc * (9 * COUT * 16);
#define STAGEB(U)                                                             \
  {                                                                           \
    int u = (U);                                                              \
    int v = u >> 7, q = u & 127;                                              \
    int nl = q >> 1, half = q & 1;                                            \
    size_t srcE = (size_t)v * (COUT * 16) + (size_t)(nb * 64 + nl) * 16 +     \
                  half * 8;                                                   \
    int dst = 9216 + v * 1024 + nl * 16 + half * 8;                           \
    *reinterpret_cast<float4*>(&lds[dst]) =                                   \
        *reinterpret_cast<const float4*>(&bsrc[srcE]);                        \
  }
      STAGEB(t)
      STAGEB(256 + t)
      STAGEB(512 + t)
      STAGEB(768 + t)
      if (t < 128) STAGEB(1024 + t)
#undef STAGEB
    }
    __syncthreads();

    // ---- compute: 9 v-steps x 1 product ----
#pragma unroll
    for (int v = 0; v < 9; ++v) {
      const char* lbc = reinterpret_cast<const char*>(lds);
      bf16x8 ah = *reinterpret_cast<const bf16x8*>(lbc + v * 2048 + aoff);
      bf16x8 bh =
          *reinterpret_cast<const bf16x8*>(lbc + 18432 + v * 2048 + boff);
      acc = __builtin_amdgcn_mfma_f32_32x32x16_bf16(ah, bh, acc, 0, 0, 0);
    }
  }

  // ---- epilogue: C/D layout col=lane&31, row=(reg&3)+8*(reg>>2)+4*(lane>>5)
  float* p = part + (size_t)blockIdx.z * M * COUT;
  const int gn = nb * 64 + wn * 32 + frow;
#pragma unroll
  for (int r = 0; r < 16; ++r) {
    int mlocal = (r & 3) + 8 * (r >> 2) + 4 * fkg;
    int gm = mbase + wm * 32 + mlocal;
    p[(size_t)gm * COUT + gn] = acc[r];
  }
}

// ---------------------------------------------------------------------------
// Reduce split-K partials (round-25: COALESCED part reads — thread map is
// part-layout-major, o fastest; the single scattered act/E write is absorbed
// by L2 write-combining; reads were stride-COUT at 1/16 line efficiency).
// ---------------------------------------------------------------------------
template <int COUT, int HO, int WO>
__global__ __launch_bounds__(256) void reduce_pe_pack(
    const float* __restrict__ part, uint32_t* __restrict__ E, int SK) {
  constexpr int M = BATCH * HO * WO;
  int idx = blockIdx.x * 256 + threadIdx.x;  // = m*COUT + o (part layout)
  float s = 0.f;
  for (int k = 0; k < SK; ++k) s += part[(size_t)k * M * COUT + idx];
  int o = idx & (COUT - 1);
  int m = idx / COUT;
  int b = m / (HO * WO);
  int hw = m % (HO * WO);
  int idx2 = ((b * COUT + o) * (HO * WO)) + hw;  // act layout
  float e[9];
  expand9(s, e);
  uint32_t d[5];
  pack9(e, d);
  uint4* p = reinterpret_cast<uint4*>(E + (size_t)idx2 * 8);
  p[0] = make_uint4(d[0], d[1], d[2], d[3]);
  p[1] = make_uint4(d[4], 0u, 0u, 0u);
}

template <int COUT, int HO, int WO>
__global__ __launch_bounds__(256) void reduce_p(
    const float* __restrict__ part, float* __restrict__ act, int SK) {
  constexpr int M = BATCH * HO * WO;
  int idx = blockIdx.x * 256 + threadIdx.x;  // = m*COUT + o (part layout)
  float s = 0.f;
  for (int k = 0; k < SK; ++k) s += part[(size_t)k * M * COUT + idx];
  int o = idx & (COUT - 1);
  int m = idx / COUT;
  int b = m / (HO * WO);
  int hw = m % (HO * WO);
  act[((b * COUT + o) * (HO * WO)) + hw] = s;
}

// ---------------------------------------------------------------------------
// L4 v9: round-21 proven body, q-split 4 -> 2x2 across blocks (grid 4096,
// disjoint h rows -> same p4 buffer, no extra reduction).
// ---------------------------------------------------------------------------
template <int PH, int PW>
__device__ void l4v9_wave(const float* __restrict__ eLds,
                          const float* __restrict__ WnB,
                          const float* __restrict__ ez, int lane, int bb,
                          int cs, int qh, float* __restrict__ p4) {
  constexpr int PC = PH * 2 + PW;
  const int j = lane & 15;
  const int i0 = (lane >> 4) << 2;
#pragma unroll 1
  for (int q = 2 * qh; q < 2 * qh + 2; ++q) {
    const int i = i0 + q;
    float acc[3] = {0.f, 0.f, 0.f};
#pragma unroll
    for (int a = 0; a < 2; ++a) {
      const int gi = i + PH - 1 + a;
      const bool vr = (unsigned)gi < 16u;
#pragma unroll
      for (int b2 = 0; b2 < 2; ++b2) {
        const int gj = j + PW - 1 + b2;
        const bool ok = vr && ((unsigned)gj < 16u);
        const int pp = ok ? (gi * 16 + gj) : 0;  // clamped safe address
        const int nbi = a * 2 + b2;
#pragma unroll
        for (int cl = 0; cl < 2; ++cl) {
          const float* ep = eLds + cl * 2304 + pp * 9;
          float en[9];
#pragma unroll
          for (int v = 0; v < 9; ++v) en[v] = ok ? ep[v] : ez[v];
          const float* wp = WnB + ((cl * 4 + PC) * 4 + nbi) * 27;
#pragma unroll
          for (int v = 0; v < 9; ++v) {
            acc[0] = fmaf(en[v], wp[v * 3 + 0], acc[0]);
            acc[1] = fmaf(en[v], wp[v * 3 + 1], acc[1]);
            acc[2] = fmaf(en[v], wp[v * 3 + 2], acc[2]);
          }
        }
      }
    }
    const int h = (i << 1) + PH, w = (j << 1) + PW;
#pragma unroll
    for (int o = 0; o < 3; ++o)
      p4[(size_t)cs * 196608 + ((bb * 3 + o) << 10) + (h << 5) + w] = acc[o];
  }
}

__global__ __launch_bounds__(256) void kan_l4_v9(
    const float* __restrict__ a3, const float* __restrict__ Wn,
    float* __restrict__ p4) {
  __shared__ float eLds[2 * 256 * 9];  // 18.4 KB
  const int bid = blockIdx.x;          // 64 bb x 32 cs x 2 qh
  const int qh = bid & 1, cs = (bid >> 1) & 31, bb = bid >> 6;
  const int t = threadIdx.x;
  float ez[9];
  expand9(0.f, ez);
#pragma unroll
  for (int cl = 0; cl < 2; ++cl) {
    float x = a3[(size_t)(bb * 64 + cs * 2 + cl) * 256 + t];
    float ev[9];
    expand9(x, ev);
#pragma unroll
    for (int v = 0; v < 9; ++v) eLds[(cl * 256 + t) * 9 + v] = ev[v];
  }
  __syncthreads();
  const int wv_ = t >> 6, lane = t & 63;
  const float* WnB = Wn + (size_t)cs * 2 * (4 * 4 * 27);
  if (wv_ == 0)
    l4v9_wave<0, 0>(eLds, WnB, ez, lane, bb, cs, qh, p4);
  else if (wv_ == 1)
    l4v9_wave<0, 1>(eLds, WnB, ez, lane, bb, cs, qh, p4);
  else if (wv_ == 2)
    l4v9_wave<1, 0>(eLds, WnB, ez, lane, bb, cs, qh, p4);
  else
    l4v9_wave<1, 1>(eLds, WnB, ez, lane, bb, cs, qh, p4);
}

__global__ __launch_bounds__(256) void reduce_tanh_l4_32(
    const float* __restrict__ p4, float* __restrict__ out) {
  int i = blockIdx.x * 256 + threadIdx.x;  // 196608
  float s = 0.f;
#pragma unroll
  for (int k = 0; k < 32; ++k) s += p4[(size_t)k * 196608 + i];
  out[i] = tanhf(s);
}

__global__ __launch_bounds__(256) void reduce_tanh_l4(
    const float* __restrict__ p4, float* __restrict__ out) {
  int i = blockIdx.x * 256 + threadIdx.x;
  float s = p4[i] + p4[i + 196608] + p4[i + 2 * 196608] + p4[i + 3 * 196608];
  out[i] = tanhf(s);
}

// ---------------------------------------------------------------------------
// Fallback path (round-1 proven) for small workspace
// ---------------------------------------------------------------------------
template <int CIN, int COUT, int HO, int WO, int BN, int SK>
__global__ __launch_bounds__(256) void kan_gemm(
    const float* __restrict__ in, const float* __restrict__ bw,
    const float* __restrict__ sw, const float* __restrict__ ss,
    float* __restrict__ outp) {
  constexpr int BM = 64, TM = 4, TN = 4, FC = 16;
  constexpr int F = CIN * 9;
  constexpr int HI = HO / 2, WI = WO / 2;
  constexpr int M = BATCH * HO * WO;
  constexpr int FPB = F / SK;

  __shared__ float Ae[FC * 9][BM];

  const int t = threadIdx.x;
  const int mbase = blockIdx.x * BM;
  const int obase = blockIdx.y * BN;
  const int f0 = blockIdx.z * FPB;

  const int cg = t & (BN / TN - 1);
  const int rg = t / (BN / TN);
  const int m0 = rg * TM;
  const int o0 = obase + cg * TN;

  float acc[TM][TN] = {};

  for (int fc = f0; fc < f0 + FPB; fc += FC) {
#pragma unroll
    for (int j = 0; j < BM * FC / 256; ++j) {
      int p = j * 256 + t;
      int ml = p & (BM - 1);
      int df = p >> 6;
      int f = fc + df;
      int c = f / 9;
      int r = f - c * 9;
      int kh = r / 3, kw = r - kh * 3;
      int m = mbase + ml;
      int bb = m / (HO * WO);
      int rem = m % (HO * WO);
      int hh = rem / WO, ww = rem % WO;
      int hp = hh + kh - 1, wp = ww + kw - 1;
      float val = 0.f;
      if (hp >= 0 && hp < HO && wp >= 0 && wp < WO)
        val = in[((bb * CIN + c) * HI + (hp >> 1)) * WI + (wp >> 1)];
      float e[9];
      expand9(val, e);
#pragma unroll
      for (int v = 0; v < 9; ++v) Ae[df * 9 + v][ml] = e[v];
    }
    __syncthreads();

#pragma unroll 2
    for (int df = 0; df < FC; ++df) {
      int f = fc + df;
      float wb[TN], wsv[TN][8];
#pragma unroll
      for (int tn = 0; tn < TN; ++tn) {
        int i = (o0 + tn) * F + f;
        wb[tn] = bw[i];
        float sc = ss[i];
        const float4* sp = reinterpret_cast<const float4*>(sw + (size_t)i * 8);
        float4 s0 = sp[0], s1 = sp[1];
        wsv[tn][0] = s0.x * sc; wsv[tn][1] = s0.y * sc;
        wsv[tn][2] = s0.z * sc; wsv[tn][3] = s0.w * sc;
        wsv[tn][4] = s1.x * sc; wsv[tn][5] = s1.y * sc;
        wsv[tn][6] = s1.z * sc; wsv[tn][7] = s1.w * sc;
      }
      float a[9][TM];
#pragma unroll
      for (int v = 0; v < 9; ++v) {
        float4 q = *reinterpret_cast<const float4*>(&Ae[df * 9 + v][m0]);
        a[v][0] = q.x; a[v][1] = q.y; a[v][2] = q.z; a[v][3] = q.w;
      }
#pragma unroll
      for (int tm = 0; tm < TM; ++tm)
#pragma unroll
        for (int tn = 0; tn < TN; ++tn) acc[tm][tn] += a[0][tm] * wb[tn];
#pragma unroll
      for (int v = 1; v < 9; ++v)
#pragma unroll
        for (int tm = 0; tm < TM; ++tm)
#pragma unroll
          for (int tn = 0; tn < TN; ++tn)
            acc[tm][tn] += a[v][tm] * wsv[tn][v - 1];
    }
    __syncthreads();
  }

  if constexpr (SK > 1) {
    float* p = outp + (size_t)blockIdx.z * M * COUT;
#pragma unroll
    for (int tm = 0; tm < TM; ++tm) {
      int m = mbase + m0 + tm;
#pragma unroll
      for (int tn = 0; tn < TN; ++tn)
        p[(size_t)m * COUT + (o0 + tn)] = acc[tm][tn];
    }
  } else {
#pragma unroll
    for (int tm = 0; tm < TM; ++tm) {
      int m = mbase + m0 + tm;
      int bb = m / (HO * WO);
      int rem = m % (HO * WO);
      int hh = rem / WO, ww = rem % WO;
#pragma unroll
      for (int tn = 0; tn < TN; ++tn) {
        int o = o0 + tn;
        outp[((bb * COUT + o) * HO + hh) * WO + ww] = acc[tm][tn];
      }
    }
  }
}

template <int COUT, int HO, int WO, int SK>
__global__ __launch_bounds__(256) void reduce_partials_old(
    const float* __restrict__ part, float* __restrict__ act) {
  constexpr int M = BATCH * HO * WO;
  int idx = blockIdx.x * 256 + threadIdx.x;
  if (idx >= M * COUT) return;
  float s = 0.f;
#pragma unroll
  for (int k = 0; k < SK; ++k) s += part[(size_t)k * M * COUT + idx];
  int m = idx / COUT, o = idx - (idx / COUT) * COUT;
  int bb = m / (HO * WO);
  int rem = m % (HO * WO);
  int hh = rem / WO, ww = rem % WO;
  act[((bb * COUT + o) * HO + hh) * WO + ww] = s;
}

__global__ __launch_bounds__(256) void kan_l4_split(
    const float* __restrict__ a3, const float* __restrict__ bw,
    const float* __restrict__ sw, const float* __restrict__ ss,
    float* __restrict__ p4) {
  int tid = blockIdx.x * 256 + threadIdx.x;
  int cs = tid >> 16, pix = tid & 65535;
  int b = pix >> 10, rem = pix & 1023, h = rem >> 5, w = rem & 31;
  float acc[3] = {0.f, 0.f, 0.f};
  for (int c = cs * 16; c < cs * 16 + 16; ++c) {
#pragma unroll
    for (int kh = 0; kh < 3; ++kh) {
#pragma unroll
      for (int kw = 0; kw < 3; ++kw) {
        int f = (c * 3 + kh) * 3 + kw;
        int hp = h + kh - 1, wp = w + kw - 1;
        float x = 0.f;
        if ((unsigned)hp < 32u && (unsigned)wp < 32u)
          x = a3[((b * 64 + c) * 16 + (hp >> 1)) * 16 + (wp >> 1)];
        float e[9];
        expand9(x, e);
#pragma unroll
        for (int o = 0; o < 3; ++o) {
          int i = o * 576 + f;
          float d = e[1] * sw[i * 8 + 0];
#pragma unroll
          for (int v = 1; v < 8; ++v) d += e[v + 1] * sw[i * 8 + v];
          acc[o] += e[0] * bw[i] + d * ss[i];
        }
      }
    }
  }
#pragma unroll
  for (int o = 0; o < 3; ++o)
    p4[cs * 196608 + ((b * 3 + o) << 10) + (h << 5) + w] = acc[o];
}

// ---------------------------------------------------------------------------
extern "C" void kernel_launch(void* const* d_in, const int* in_sizes, int n_in,
                              void* d_out, int out_size, void* d_ws,
                              size_t ws_size, hipStream_t stream) {
  const float* x     = (const float*)d_in[0];
  const float* lin_w = (const float*)d_in[1];
  const float* lin_b = (const float*)d_in[2];
  const float* bw1 = (const float*)d_in[3];
  const float* sw1 = (const float*)d_in[4];
  const float* ss1 = (const float*)d_in[5];
  const float* bw2 = (const float*)d_in[6];
  const float* sw2 = (const float*)d_in[7];
  const float* ss2 = (const float*)d_in[8];
  const float* bw3 = (const float*)d_in[9];
  const float* sw3 = (const float*)d_in[10];
  const float* ss3 = (const float*)d_in[11];
  const float* bw4 = (const float*)d_in[12];
  const float* sw4 = (const float*)d_in[13];
  const float* ss4 = (const float*)d_in[14];

  float* wsf = (float*)d_ws;
  // ---- main-path layout (round 25 = round 23): 16,563,200 floats = 66.3 MB
  float* h    = wsf;                                        // 131072
  float* a3   = wsf + 131072;                               // 1048576
  unsigned short* Bg1 = (unsigned short*)(wsf + 1179648);   // 5,308,416 floats
  unsigned short* Bg2 = (unsigned short*)(wsf + 6488064);   // 1,327,104 floats
  unsigned short* Bg3 = (unsigned short*)(wsf + 7815168);   //   331,776 floats
  float* wl4  = wsf + 8146944;                              //    27,648
  float* part = wsf + 8174592;                              // 4,194,304 (SK=16)
  uint32_t* Eg = (uint32_t*)(wsf + 12368896);               // 4,194,304 (8/pix)
  float* p4   = wsf + 8174592;  // aliases part+Eg (dead post-L3), 6.29M floats

  const size_t mainNeed = 16563200ull;

  if (ws_size / 4 >= mainNeed) {
    // One launch for all input-only prep: 3x bpack + wnl4 + linear+expand.
    prep_all<<<6668, 256, 0, stream>>>(
        x, lin_w, lin_b, h, Eg,
        bw1, sw1, ss1, Bg1,
        bw2, sw2, ss2, Bg2,
        bw3, sw3, ss3, Bg3,
        bw4, sw4, ss4, wl4);

    // L1: CIN=512 COUT=256 4x4, SK=16 (1024 blocks, CPB=18)
    gemm_mfma<512, 256, 4, 4, 16>
        <<<dim3(16, 4, 16), 256, 0, stream>>>(Eg, Bg1, part);
    reduce_pe_pack<256, 4, 4><<<1024, 256, 0, stream>>>(part, Eg, 16);

    // L2: CIN=256 COUT=128 8x8, SK=8 (1024 blocks, CPB=18)
    gemm_mfma<256, 128, 8, 8, 8>
        <<<dim3(64, 2, 8), 256, 0, stream>>>(Eg, Bg2, part);
    reduce_pe_pack<128, 8, 8><<<2048, 256, 0, stream>>>(part, Eg, 8);

    // L3: CIN=128 COUT=64 16x16, SK=4 (1024 blocks, CPB=18)
    gemm_mfma<128, 64, 16, 16, 4>
        <<<dim3(256, 1, 4), 256, 0, stream>>>(Eg, Bg3, part);
    reduce_p<64, 16, 16><<<4096, 256, 0, stream>>>(part, a3, 4);

    // L4: 32 channel groups x 2 q-halves (4096 blocks) + tanh reduce
    kan_l4_v9<<<4096, 256, 0, stream>>>(a3, wl4, p4);
    reduce_tanh_l4_32<<<768, 256, 0, stream>>>(p4, (float*)d_out);
  } else {
    // round-1 proven fallback (needs ~16.3 MB), original layout
    float* hF  = wsf;
    float* a1F = hF + 131072;
    float* a2F = a1F + 262144;
    float* a3F = a2F + 524288;
    float* partOld = a3F + 1048576;
    linear_relu_only<<<512, 256, 0, stream>>>(x, lin_w, lin_b, hF);
    kan_gemm<512, 256, 4, 4, 64, 8>
        <<<dim3(16, 4, 8), 256, 0, stream>>>(hF, bw1, sw1, ss1, partOld);
    reduce_partials_old<256, 4, 4, 8><<<1024, 256, 0, stream>>>(partOld, a1F);
    kan_gemm<256, 128, 8, 8, 64, 2>
        <<<dim3(64, 2, 2), 256, 0, stream>>>(a1F, bw2, sw2, ss2, partOld);
    reduce_partials_old<128, 8, 8, 2><<<2048, 256, 0, stream>>>(partOld, a2F);
    kan_gemm<128, 64, 16, 16, 64, 1>
        <<<dim3(256, 1, 1), 256, 0, stream>>>(a2F, bw3, sw3, ss3, a3F);
    kan_l4_split<<<1024, 256, 0, stream>>>(a3F, bw4, sw4, ss4, partOld);
    reduce_tanh_l4<<<768, 256, 0, stream>>>(partOld, (float*)d_out);
  }
}

// Round 26
// 242.440 us; speedup vs baseline: 1.4532x; 1.0671x over previous
//
#include <hip/hip_runtime.h>
#include <cstdint>
#include <cmath>

#define BATCH 64

typedef __attribute__((ext_vector_type(8))) __bf16 bf16x8;
typedef __attribute__((ext_vector_type(16))) float f32x16;

// ---------------------------------------------------------------------------
// Spline + silu expansion: x -> [silu(x), B_0(x) .. B_7(x)]
// ---------------------------------------------------------------------------
__device__ __forceinline__ void expand9(float x, float* e) {
  float t = __expf(-x);
  e[0] = __fdividef(x, 1.f + t);  // silu
  float b[11];
#pragma unroll
  for (int j = 0; j < 11; ++j) {
    float gj  = 0.4f * (float)j - 2.2f;
    float gj1 = 0.4f * (float)(j + 1) - 2.2f;
    b[j] = (x >= gj && x < gj1) ? 1.f : 0.f;
  }
#pragma unroll
  for (int k = 1; k <= 3; ++k) {
    float inv = 1.f / (0.4f * (float)k);
#pragma unroll
    for (int j = 0; j < 11 - k; ++j) {
      float gj   = 0.4f * (float)j - 2.2f;
      float gjk1 = 0.4f * (float)(j + k + 1) - 2.2f;
      b[j] = ((x - gj) * b[j] + (gjk1 - x) * b[j + 1]) * inv;
    }
  }
#pragma unroll
  for (int v = 0; v < 8; ++v) e[v + 1] = b[v];
}

// bf16 helper (round-to-nearest-even)
__device__ __forceinline__ unsigned short f2bf(float x) {
  uint32_t u = __float_as_uint(x);
  uint32_t r = u + 0x7fffu + ((u >> 16) & 1u);
  return (unsigned short)(r >> 16);
}

// Pack 9 bf16 values into 5 dwords (pairs): d[i] = bf[2i] | bf[2i+1]<<16.
__device__ __forceinline__ void pack9(const float* e, uint32_t* d) {
  d[0] = (uint32_t)f2bf(e[0]) | ((uint32_t)f2bf(e[1]) << 16);
  d[1] = (uint32_t)f2bf(e[2]) | ((uint32_t)f2bf(e[3]) << 16);
  d[2] = (uint32_t)f2bf(e[4]) | ((uint32_t)f2bf(e[5]) << 16);
  d[3] = (uint32_t)f2bf(e[6]) | ((uint32_t)f2bf(e[7]) << 16);
  d[4] = (uint32_t)f2bf(e[8]);
}

// ---------------------------------------------------------------------------
// Parity-presummed weight prep (round 26): for output parity pc=(PH,PW), the
// 9 conv taps collapse onto 4 input neighbors nb=(a,b2); taps sharing a
// neighbor see the SAME input value (incl. padded-zero expansion), so their
// weights pre-sum exactly (identity proven in L4 since round 9).
// Bn[pc][kcn][v][n][fl16], feature = c*4+nb: kcn = c>>2, fl = (c&3)*4+nb.
// Thread per (n,c): reads raw weights ONCE (contiguous), writes 36 uint2.
// ---------------------------------------------------------------------------
template <int CIN, int N, int LOGN>
__device__ __forceinline__ void presum_body(int bid,
                                            const float* __restrict__ bw,
                                            const float* __restrict__ sw,
                                            const float* __restrict__ ss,
                                            unsigned short* __restrict__ Bn) {
  constexpr int F = CIN * 9;
  constexpr int KCN = CIN / 4;
  int idx = bid * 256 + threadIdx.x;  // over CIN*N
  int n = idx & (N - 1);
  int c = idx >> LOGN;
  const float* bwp = bw + (size_t)n * F + c * 9;
  const float* ssp = ss + (size_t)n * F + c * 9;
  const float* swp = sw + ((size_t)n * F + c * 9) * 8;
  float ssv[9];
#pragma unroll
  for (int t2 = 0; t2 < 9; ++t2) ssv[t2] = ssp[t2];
  const int kcn = c >> 2;
  const int flb = (c & 3) * 4;
#pragma unroll
  for (int v = 0; v < 9; ++v) {
    float tv[9];
#pragma unroll
    for (int t2 = 0; t2 < 9; ++t2)
      tv[t2] = (v == 0) ? bwp[t2] : swp[t2 * 8 + (v - 1)] * ssv[t2];
#pragma unroll
    for (int pc = 0; pc < 4; ++pc) {
      const int PH = pc >> 1, PW = pc & 1;
      unsigned short u[4];
#pragma unroll
      for (int nb = 0; nb < 4; ++nb) {
        const int a = nb >> 1, b2 = nb & 1;
        float s = 0.f;
#pragma unroll
        for (int kh = 0; kh < 3; ++kh) {
          if (((kh > PH) ? 1 : 0) != a) continue;
#pragma unroll
          for (int kw = 0; kw < 3; ++kw) {
            if (((kw > PW) ? 1 : 0) != b2) continue;
            s += tv[kh * 3 + kw];
          }
        }
        u[nb] = f2bf(s);
      }
      size_t off = ((((size_t)pc * KCN + kcn) * 9 + v) * N + n) * 16 + flb;
      *reinterpret_cast<uint2*>(Bn + off) =
          make_uint2((uint32_t)u[0] | ((uint32_t)u[1] << 16),
                     (uint32_t)u[2] | ((uint32_t)u[3] << 16));
    }
  }
}

__device__ __forceinline__ void wnl4_body(int bid, const float* __restrict__ bw,
                                          const float* __restrict__ sw,
                                          const float* __restrict__ ss,
                                          float* __restrict__ Wn) {
  int idx = bid * 256 + threadIdx.x;  // 27648 exactly
  if (idx >= 27648) return;
  int u = idx % 27;
  int o = u % 3, v = u / 3;
  int rest = idx / 27;
  int nb = rest & 3;
  rest >>= 2;
  int pc = rest & 3;
  rest >>= 2;
  int c = rest;
  int PH = pc >> 1, PW = pc & 1;
  int a = nb >> 1, b2 = nb & 1;
  float s = 0.f;
#pragma unroll
  for (int kh = 0; kh < 3; ++kh) {
    if (((kh > PH) ? 1 : 0) != a) continue;
#pragma unroll
    for (int kw = 0; kw < 3; ++kw) {
      if (((kw > PW) ? 1 : 0) != b2) continue;
      int f = c * 9 + kh * 3 + kw;
      float wv = (v == 0)
                     ? bw[o * 576 + f]
                     : sw[((size_t)(o * 576 + f)) * 8 + (v - 1)] * ss[o * 576 + f];
      s += wv;
    }
  }
  Wn[idx] = s;
}

__device__ __forceinline__ void linear_body(int bid, const float* __restrict__ x,
                                            const float* __restrict__ w,
                                            const float* __restrict__ bias,
                                            float* __restrict__ h,
                                            uint32_t* __restrict__ E) {
  int idx = bid * 256 + threadIdx.x;  // 64*2048
  int b = idx >> 11, o = idx & 2047;
  const float* xr = x + b * 100;
  const float* wr = w + o * 100;
  float acc = bias[o];
#pragma unroll 4
  for (int k = 0; k < 100; ++k) acc += xr[k] * wr[k];
  float hv = fmaxf(acc, 0.f);
  h[idx] = hv;
  float e[9];
  expand9(hv, e);
  uint32_t d[5];
  pack9(e, d);
  uint4* p = reinterpret_cast<uint4*>(E + (size_t)idx * 8);
  p[0] = make_uint4(d[0], d[1], d[2], d[3]);
  p[1] = make_uint4(d[4], 0u, 0u, 0u);
}

// Launch 1: presum L1 + wnl4 + linear.  512 + 108 + 512 = 1132 blocks.
__global__ __launch_bounds__(256) void prep_main(
    const float* __restrict__ x, const float* __restrict__ lin_w,
    const float* __restrict__ lin_b, float* __restrict__ h,
    uint32_t* __restrict__ Eg,
    const float* __restrict__ bw1, const float* __restrict__ sw1,
    const float* __restrict__ ss1, unsigned short* __restrict__ Bn1,
    const float* __restrict__ bw4, const float* __restrict__ sw4,
    const float* __restrict__ ss4, float* __restrict__ wl4) {
  int bid = blockIdx.x;
  if (bid < 512) { presum_body<512, 256, 8>(bid, bw1, sw1, ss1, Bn1); return; }
  bid -= 512;
  if (bid < 108) { wnl4_body(bid, bw4, sw4, ss4, wl4); return; }
  bid -= 108;
  linear_body(bid, x, lin_w, lin_b, h, Eg);
}

// Launch after L1 gemm: presum L2 + L3 into the (dead) Bn1 region.
__global__ __launch_bounds__(256) void prep23(
    const float* __restrict__ bw2, const float* __restrict__ sw2,
    const float* __restrict__ ss2, unsigned short* __restrict__ Bn2,
    const float* __restrict__ bw3, const float* __restrict__ sw3,
    const float* __restrict__ ss3, unsigned short* __restrict__ Bn3) {
  int bid = blockIdx.x;
  if (bid < 128) { presum_body<256, 128, 7>(bid, bw2, sw2, ss2, Bn2); return; }
  bid -= 128;
  presum_body<128, 64, 6>(bid, bw3, sw3, ss3, Bn3);
}

// Standalone linear kernel (fallback path only)
__global__ __launch_bounds__(256) void linear_relu_only(
    const float* __restrict__ x, const float* __restrict__ w,
    const float* __restrict__ bias, float* __restrict__ h) {
  int idx = blockIdx.x * 256 + threadIdx.x;
  int b = idx >> 11, o = idx & 2047;
  const float* xr = x + b * 100;
  const float* wr = w + o * 100;
  float acc = bias[o];
#pragma unroll 4
  for (int k = 0; k < 100; ++k) acc += xr[k] * wr[k];
  h[idx] = fmaxf(acc, 0.f);
}

// ---------------------------------------------------------------------------
// Parity-presummed bf16 MFMA GEMM (round 26). K = 36*CIN (was 81*CIN).
// Grid: (M_pc/64, pc*NB+nb, SK). A-operand rows are one parity class; the
// thread's 4 staging loads are the 4 input NEIGHBORS of its channel (same
// phase-local load/pack shape as the proven LDTAP). B-staging and the MFMA
// loop are byte-identical to round 25 (Bn layout matches by construction).
// Epilogue maps class-row -> full-M row, so reduce kernels are unchanged.
// ---------------------------------------------------------------------------
template <int CIN, int COUT, int HO, int WO, int SK>
__global__ __launch_bounds__(256, 4) void gemm_mfma(
    const uint32_t* __restrict__ E, const unsigned short* __restrict__ Bn,
    float* __restrict__ part) {
  constexpr int HO2 = HO / 2, WO2 = WO / 2;
  constexpr int NKC = CIN / 4;          // K-chunks of 16 feats (4c x 4nb)
  constexpr int M = BATCH * HO * WO;
  constexpr int MPC = M / 4;
  constexpr int NB = COUT / 64;
  constexpr int CPB = NKC / SK;
  static_assert(NKC % SK == 0, "sk");

  // plane 0: A-hi [9][64][16]; plane 1: B-hi
  __shared__ __align__(16) unsigned short lds[2 * 9216];

  const int t = threadIdx.x;
  const int mbase = blockIdx.x * 64;
  const int ybn = blockIdx.y;
  const int pc = ybn / NB;
  const int nb = ybn % NB;
  const int PH = pc >> 1, PW = pc & 1;
  const int kc0 = blockIdx.z * CPB;
  const unsigned short* BgP = Bn + (size_t)pc * NKC * 9 * COUT * 16;

  uint32_t ez[5];
  {
    float e0[9];
    expand9(0.f, e0);
    pack9(e0, ez);
  }

  const int lane = t & 63, wv_ = t >> 6;
  const int wm = wv_ >> 1, wn = wv_ & 1;
  const int frow = lane & 31, fkg = lane >> 5;
  const int aoff = ((wm * 32 + frow) * 16 + fkg * 8) * 2;  // bytes
  const int boff = ((wn * 32 + frow) * 16 + fkg * 8) * 2;

  // A-staging geometry: thread covers class-row aml, channel c = kc*4 + flq,
  // and its 4 input neighbors.
  const int aml = t >> 2, flq = t & 3;
  const int am = mbase + aml;  // row within parity class
  const int ab = am / (HO2 * WO2), ahw = am % (HO2 * WO2);
  const int ihm = ahw / WO2, iwm = ahw % WO2;
  const int gi0 = ihm + PH - 1, gj0 = iwm + PW - 1;

  f32x16 acc;
#pragma unroll
  for (int i = 0; i < 16; ++i) acc[i] = 0.f;

  for (int ci = 0; ci < CPB; ++ci) {
    const int kc = kc0 + ci;
    __syncthreads();

    // ---- stage A: 4 neighbors of channel c, dwordx4 + dword each ----
    {
      const int cch = kc * 4 + flq;
      uint32_t w0[5], w1[5], w2[5], w3[5];
#define LDNB(A, B2, DST)                                                      \
  {                                                                           \
    int gi = gi0 + (A), gj = gj0 + (B2);                                      \
    if ((unsigned)gi < (unsigned)HO2 && (unsigned)gj < (unsigned)WO2) {       \
      const uint32_t* ep =                                                    \
          E + (size_t)(((ab * CIN + cch) * HO2 + gi) * WO2 + gj) * 8;         \
      uint4 q0 = *reinterpret_cast<const uint4*>(ep);                         \
      DST[0] = q0.x; DST[1] = q0.y; DST[2] = q0.z; DST[3] = q0.w;             \
      DST[4] = ep[4];                                                         \
    } else {                                                                  \
      _Pragma("unroll") for (int v = 0; v < 5; ++v) DST[v] = ez[v];           \
    }                                                                         \
  }
      LDNB(0, 0, w0)
      LDNB(0, 1, w1)
      LDNB(1, 0, w2)
      LDNB(1, 1, w3)
#undef LDNB
#define GETV(W, V) (((V)&1) ? ((W)[(V) >> 1] >> 16) : ((W)[(V) >> 1] & 0xffffu))
      char* lb = reinterpret_cast<char*>(lds);
#pragma unroll
      for (int v = 0; v < 9; ++v) {
        uint32_t t0 = GETV(w0, v), t1 = GETV(w1, v);
        uint32_t t2 = GETV(w2, v), t3 = GETV(w3, v);
        uint32_t hi01 = t0 | (t1 << 16);
        uint32_t hi23 = t2 | (t3 << 16);
        *reinterpret_cast<uint2*>(lb + v * 2048 + aml * 32 + flq * 8) =
            make_uint2(hi01, hi23);
      }
#undef GETV
    }

    // ---- stage B: one plane, 1152 float4s over 256 threads ----
    {
      const unsigned short* bsrc = BgP + (size_t)kc * (9 * COUT * 16);
#define STAGEB(U)                                                             \
  {                                                                           \
    int u = (U);                                                              \
    int v = u >> 7, q = u & 127;                                              \
    int nl = q >> 1, half = q & 1;                                            \
    size_t srcE = (size_t)v * (COUT * 16) + (size_t)(nb * 64 + nl) * 16 +     \
                  half * 8;                                                   \
    int dst = 9216 + v * 1024 + nl * 16 + half * 8;                           \
    *reinterpret_cast<float4*>(&lds[dst]) =                                   \
        *reinterpret_cast<const float4*>(&bsrc[srcE]);                        \
  }
      STAGEB(t)
      STAGEB(256 + t)
      STAGEB(512 + t)
      STAGEB(768 + t)
      if (t < 128) STAGEB(1024 + t)
#undef STAGEB
    }
    __syncthreads();

    // ---- compute: 9 v-steps x 1 product ----
#pragma unroll
    for (int v = 0; v < 9; ++v) {
      const char* lbc = reinterpret_cast<const char*>(lds);
      bf16x8 ah = *reinterpret_cast<const bf16x8*>(lbc + v * 2048 + aoff);
      bf16x8 bh =
          *reinterpret_cast<const bf16x8*>(lbc + 18432 + v * 2048 + boff);
      acc = __builtin_amdgcn_mfma_f32_32x32x16_bf16(ah, bh, acc, 0, 0, 0);
    }
  }

  // ---- epilogue: class-row -> full-M row; C/D layout as proven ----
  float* p = part + (size_t)blockIdx.z * M * COUT;
  const int gn = nb * 64 + wn * 32 + frow;
#pragma unroll
  for (int r = 0; r < 16; ++r) {
    int mlocal = (r & 3) + 8 * (r >> 2) + 4 * fkg;
    int gmp = mbase + wm * 32 + mlocal;
    int eb = gmp / (HO2 * WO2);
    int er = gmp % (HO2 * WO2);
    int eih = er / WO2, eiw = er % WO2;
    int gm = (eb * HO + 2 * eih + PH) * WO + (2 * eiw + PW);
    p[(size_t)gm * COUT + gn] = acc[r];
  }
}

// ---------------------------------------------------------------------------
// Reduce split-K partials (round-25 proven: coalesced part reads).
// ---------------------------------------------------------------------------
template <int COUT, int HO, int WO>
__global__ __launch_bounds__(256) void reduce_pe_pack(
    const float* __restrict__ part, uint32_t* __restrict__ E, int SK) {
  constexpr int M = BATCH * HO * WO;
  int idx = blockIdx.x * 256 + threadIdx.x;  // = m*COUT + o (part layout)
  float s = 0.f;
  for (int k = 0; k < SK; ++k) s += part[(size_t)k * M * COUT + idx];
  int o = idx & (COUT - 1);
  int m = idx / COUT;
  int b = m / (HO * WO);
  int hw = m % (HO * WO);
  int idx2 = ((b * COUT + o) * (HO * WO)) + hw;  // act layout
  float e[9];
  expand9(s, e);
  uint32_t d[5];
  pack9(e, d);
  uint4* p = reinterpret_cast<uint4*>(E + (size_t)idx2 * 8);
  p[0] = make_uint4(d[0], d[1], d[2], d[3]);
  p[1] = make_uint4(d[4], 0u, 0u, 0u);
}

template <int COUT, int HO, int WO>
__global__ __launch_bounds__(256) void reduce_p(
    const float* __restrict__ part, float* __restrict__ act, int SK) {
  constexpr int M = BATCH * HO * WO;
  int idx = blockIdx.x * 256 + threadIdx.x;  // = m*COUT + o (part layout)
  float s = 0.f;
  for (int k = 0; k < SK; ++k) s += part[(size_t)k * M * COUT + idx];
  int o = idx & (COUT - 1);
  int m = idx / COUT;
  int b = m / (HO * WO);
  int hw = m % (HO * WO);
  act[((b * COUT + o) * (HO * WO)) + hw] = s;
}

// ---------------------------------------------------------------------------
// L4 v9 (round-25 proven): 32 channel groups x 2 q-halves (4096 blocks).
// ---------------------------------------------------------------------------
template <int PH, int PW>
__device__ void l4v9_wave(const float* __restrict__ eLds,
                          const float* __restrict__ WnB,
                          const float* __restrict__ ez, int lane, int bb,
                          int cs, int qh, float* __restrict__ p4) {
  constexpr int PC = PH * 2 + PW;
  const int j = lane & 15;
  const int i0 = (lane >> 4) << 2;
#pragma unroll 1
  for (int q = 2 * qh; q < 2 * qh + 2; ++q) {
    const int i = i0 + q;
    float acc[3] = {0.f, 0.f, 0.f};
#pragma unroll
    for (int a = 0; a < 2; ++a) {
      const int gi = i + PH - 1 + a;
      const bool vr = (unsigned)gi < 16u;
#pragma unroll
      for (int b2 = 0; b2 < 2; ++b2) {
        const int gj = j + PW - 1 + b2;
        const bool ok = vr && ((unsigned)gj < 16u);
        const int pp = ok ? (gi * 16 + gj) : 0;  // clamped safe address
        const int nbi = a * 2 + b2;
#pragma unroll
        for (int cl = 0; cl < 2; ++cl) {
          const float* ep = eLds + cl * 2304 + pp * 9;
          float en[9];
#pragma unroll
          for (int v = 0; v < 9; ++v) en[v] = ok ? ep[v] : ez[v];
          const float* wp = WnB + ((cl * 4 + PC) * 4 + nbi) * 27;
#pragma unroll
          for (int v = 0; v < 9; ++v) {
            acc[0] = fmaf(en[v], wp[v * 3 + 0], acc[0]);
            acc[1] = fmaf(en[v], wp[v * 3 + 1], acc[1]);
            acc[2] = fmaf(en[v], wp[v * 3 + 2], acc[2]);
          }
        }
      }
    }
    const int h = (i << 1) + PH, w = (j << 1) + PW;
#pragma unroll
    for (int o = 0; o < 3; ++o)
      p4[(size_t)cs * 196608 + ((bb * 3 + o) << 10) + (h << 5) + w] = acc[o];
  }
}

__global__ __launch_bounds__(256) void kan_l4_v9(
    const float* __restrict__ a3, const float* __restrict__ Wn,
    float* __restrict__ p4) {
  __shared__ float eLds[2 * 256 * 9];  // 18.4 KB
  const int bid = blockIdx.x;          // 64 bb x 32 cs x 2 qh
  const int qh = bid & 1, cs = (bid >> 1) & 31, bb = bid >> 6;
  const int t = threadIdx.x;
  float ez[9];
  expand9(0.f, ez);
#pragma unroll
  for (int cl = 0; cl < 2; ++cl) {
    float x = a3[(size_t)(bb * 64 + cs * 2 + cl) * 256 + t];
    float ev[9];
    expand9(x, ev);
#pragma unroll
    for (int v = 0; v < 9; ++v) eLds[(cl * 256 + t) * 9 + v] = ev[v];
  }
  __syncthreads();
  const int wv_ = t >> 6, lane = t & 63;
  const float* WnB = Wn + (size_t)cs * 2 * (4 * 4 * 27);
  if (wv_ == 0)
    l4v9_wave<0, 0>(eLds, WnB, ez, lane, bb, cs, qh, p4);
  else if (wv_ == 1)
    l4v9_wave<0, 1>(eLds, WnB, ez, lane, bb, cs, qh, p4);
  else if (wv_ == 2)
    l4v9_wave<1, 0>(eLds, WnB, ez, lane, bb, cs, qh, p4);
  else
    l4v9_wave<1, 1>(eLds, WnB, ez, lane, bb, cs, qh, p4);
}

__global__ __launch_bounds__(256) void reduce_tanh_l4_32(
    const float* __restrict__ p4, float* __restrict__ out) {
  int i = blockIdx.x * 256 + threadIdx.x;  // 196608
  float s = 0.f;
#pragma unroll
  for (int k = 0; k < 32; ++k) s += p4[(size_t)k * 196608 + i];
  out[i] = tanhf(s);
}

__global__ __launch_bounds__(256) void reduce_tanh_l4(
    const float* __restrict__ p4, float* __restrict__ out) {
  int i = blockIdx.x * 256 + threadIdx.x;
  float s = p4[i] + p4[i + 196608] + p4[i + 2 * 196608] + p4[i + 3 * 196608];
  out[i] = tanhf(s);
}

// ---------------------------------------------------------------------------
// Fallback path (round-1 proven) for small workspace
// ---------------------------------------------------------------------------
template <int CIN, int COUT, int HO, int WO, int BN, int SK>
__global__ __launch_bounds__(256) void kan_gemm(
    const float* __restrict__ in, const float* __restrict__ bw,
    const float* __restrict__ sw, const float* __restrict__ ss,
    float* __restrict__ outp) {
  constexpr int BM = 64, TM = 4, TN = 4, FC = 16;
  constexpr int F = CIN * 9;
  constexpr int HI = HO / 2, WI = WO / 2;
  constexpr int M = BATCH * HO * WO;
  constexpr int FPB = F / SK;

  __shared__ float Ae[FC * 9][BM];

  const int t = threadIdx.x;
  const int mbase = blockIdx.x * BM;
  const int obase = blockIdx.y * BN;
  const int f0 = blockIdx.z * FPB;

  const int cg = t & (BN / TN - 1);
  const int rg = t / (BN / TN);
  const int m0 = rg * TM;
  const int o0 = obase + cg * TN;

  float acc[TM][TN] = {};

  for (int fc = f0; fc < f0 + FPB; fc += FC) {
#pragma unroll
    for (int j = 0; j < BM * FC / 256; ++j) {
      int p = j * 256 + t;
      int ml = p & (BM - 1);
      int df = p >> 6;
      int f = fc + df;
      int c = f / 9;
      int r = f - c * 9;
      int kh = r / 3, kw = r - kh * 3;
      int m = mbase + ml;
      int bb = m / (HO * WO);
      int rem = m % (HO * WO);
      int hh = rem / WO, ww = rem % WO;
      int hp = hh + kh - 1, wp = ww + kw - 1;
      float val = 0.f;
      if (hp >= 0 && hp < HO && wp >= 0 && wp < WO)
        val = in[((bb * CIN + c) * HI + (hp >> 1)) * WI + (wp >> 1)];
      float e[9];
      expand9(val, e);
#pragma unroll
      for (int v = 0; v < 9; ++v) Ae[df * 9 + v][ml] = e[v];
    }
    __syncthreads();

#pragma unroll 2
    for (int df = 0; df < FC; ++df) {
      int f = fc + df;
      float wb[TN], wsv[TN][8];
#pragma unroll
      for (int tn = 0; tn < TN; ++tn) {
        int i = (o0 + tn) * F + f;
        wb[tn] = bw[i];
        float sc = ss[i];
        const float4* sp = reinterpret_cast<const float4*>(sw + (size_t)i * 8);
        float4 s0 = sp[0], s1 = sp[1];
        wsv[tn][0] = s0.x * sc; wsv[tn][1] = s0.y * sc;
        wsv[tn][2] = s0.z * sc; wsv[tn][3] = s0.w * sc;
        wsv[tn][4] = s1.x * sc; wsv[tn][5] = s1.y * sc;
        wsv[tn][6] = s1.z * sc; wsv[tn][7] = s1.w * sc;
      }
      float a[9][TM];
#pragma unroll
      for (int v = 0; v < 9; ++v) {
        float4 q = *reinterpret_cast<const float4*>(&Ae[df * 9 + v][m0]);
        a[v][0] = q.x; a[v][1] = q.y; a[v][2] = q.z; a[v][3] = q.w;
      }
#pragma unroll
      for (int tm = 0; tm < TM; ++tm)
#pragma unroll
        for (int tn = 0; tn < TN; ++tn) acc[tm][tn] += a[0][tm] * wb[tn];
#pragma unroll
      for (int v = 1; v < 9; ++v)
#pragma unroll
        for (int tm = 0; tm < TM; ++tm)
#pragma unroll
          for (int tn = 0; tn < TN; ++tn)
            acc[tm][tn] += a[v][tm] * wsv[tn][v - 1];
    }
    __syncthreads();
  }

  if constexpr (SK > 1) {
    float* p = outp + (size_t)blockIdx.z * M * COUT;
#pragma unroll
    for (int tm = 0; tm < TM; ++tm) {
      int m = mbase + m0 + tm;
#pragma unroll
      for (int tn = 0; tn < TN; ++tn)
        p[(size_t)m * COUT + (o0 + tn)] = acc[tm][tn];
    }
  } else {
#pragma unroll
    for (int tm = 0; tm < TM; ++tm) {
      int m = mbase + m0 + tm;
      int bb = m / (HO * WO);
      int rem = m % (HO * WO);
      int hh = rem / WO, ww = rem % WO;
#pragma unroll
      for (int tn = 0; tn < TN; ++tn) {
        int o = o0 + tn;
        outp[((bb * COUT + o) * HO + hh) * WO + ww] = acc[tm][tn];
      }
    }
  }
}

template <int COUT, int HO, int WO, int SK>
__global__ __launch_bounds__(256) void reduce_partials_old(
    const float* __restrict__ part, float* __restrict__ act) {
  constexpr int M = BATCH * HO * WO;
  int idx = blockIdx.x * 256 + threadIdx.x;
  if (idx >= M * COUT) return;
  float s = 0.f;
#pragma unroll
  for (int k = 0; k < SK; ++k) s += part[(size_t)k * M * COUT + idx];
  int m = idx / COUT, o = idx - (idx / COUT) * COUT;
  int bb = m / (HO * WO);
  int rem = m % (HO * WO);
  int hh = rem / WO, ww = rem % WO;
  act[((bb * COUT + o) * HO + hh) * WO + ww] = s;
}

__global__ __launch_bounds__(256) void kan_l4_split(
    const float* __restrict__ a3, const float* __restrict__ bw,
    const float* __restrict__ sw, const float* __restrict__ ss,
    float* __restrict__ p4) {
  int tid = blockIdx.x * 256 + threadIdx.x;
  int cs = tid >> 16, pix = tid & 65535;
  int b = pix >> 10, rem = pix & 1023, h = rem >> 5, w = rem & 31;
  float acc[3] = {0.f, 0.f, 0.f};
  for (int c = cs * 16; c < cs * 16 + 16; ++c) {
#pragma unroll
    for (int kh = 0; kh < 3; ++kh) {
#pragma unroll
      for (int kw = 0; kw < 3; ++kw) {
        int f = (c * 3 + kh) * 3 + kw;
        int hp = h + kh - 1, wp = w + kw - 1;
        float x = 0.f;
        if ((unsigned)hp < 32u && (unsigned)wp < 32u)
          x = a3[((b * 64 + c) * 16 + (hp >> 1)) * 16 + (wp >> 1)];
        float e[9];
        expand9(x, e);
#pragma unroll
        for (int o = 0; o < 3; ++o) {
          int i = o * 576 + f;
          float d = e[1] * sw[i * 8 + 0];
#pragma unroll
          for (int v = 1; v < 8; ++v) d += e[v + 1] * sw[i * 8 + v];
          acc[o] += e[0] * bw[i] + d * ss[i];
        }
      }
    }
  }
#pragma unroll
  for (int o = 0; o < 3; ++o)
    p4[cs * 196608 + ((b * 3 + o) << 10) + (h << 5) + w] = acc[o];
}

// ---------------------------------------------------------------------------
extern "C" void kernel_launch(void* const* d_in, const int* in_sizes, int n_in,
                              void* d_out, int out_size, void* d_ws,
                              size_t ws_size, hipStream_t stream) {
  const float* x     = (const float*)d_in[0];
  const float* lin_w = (const float*)d_in[1];
  const float* lin_b = (const float*)d_in[2];
  const float* bw1 = (const float*)d_in[3];
  const float* sw1 = (const float*)d_in[4];
  const float* ss1 = (const float*)d_in[5];
  const float* bw2 = (const float*)d_in[6];
  const float* sw2 = (const float*)d_in[7];
  const float* ss2 = (const float*)d_in[8];
  const float* bw3 = (const float*)d_in[9];
  const float* sw3 = (const float*)d_in[10];
  const float* ss3 = (const float*)d_in[11];
  const float* bw4 = (const float*)d_in[12];
  const float* sw4 = (const float*)d_in[13];
  const float* ss4 = (const float*)d_in[14];

  float* wsf = (float*)d_ws;
  // ---- main-path layout (round 26): 19,033,088 floats = 76.1 MB ----
  float* h    = wsf;                                        // 131072
  float* a3   = wsf + 131072;                               // 1048576
  unsigned short* Bn1 = (unsigned short*)(wsf + 1179648);   // 9,437,184 floats
  // Bn2/Bn3 prepped into Bn1's region AFTER the L1 gemm (Bn1 dead then):
  unsigned short* Bn2 = (unsigned short*)(wsf + 1179648);   // 2,359,296 floats
  unsigned short* Bn3 = (unsigned short*)(wsf + 3538944);   //   589,824 floats
  float* wl4  = wsf + 10616832;                             //    27,648
  float* part = wsf + 10644480;                             // 4,194,304 (SK=16)
  uint32_t* Eg = (uint32_t*)(wsf + 14838784);               // 4,194,304 (8/pix)
  float* p4   = wsf + 10644480;  // aliases part+Eg (dead post-L3), 6.29M

  const size_t mainNeed = 19033088ull;

  if (ws_size / 4 >= mainNeed) {
    // Prep: presum L1 + wnl4 + linear+expand (one launch).
    prep_main<<<1132, 256, 0, stream>>>(
        x, lin_w, lin_b, h, Eg,
        bw1, sw1, ss1, Bn1,
        bw4, sw4, ss4, wl4);

    // L1: CIN=512 COUT=256 4x4, SK=16 — grid (4, 4nb*4pc=16, 16), CPB=8
    gemm_mfma<512, 256, 4, 4, 16>
        <<<dim3(4, 16, 16), 256, 0, stream>>>(Eg, Bn1, part);
    // Presum L2+L3 into the now-dead Bn1 region.
    prep23<<<160, 256, 0, stream>>>(bw2, sw2, ss2, Bn2, bw3, sw3, ss3, Bn3);
    reduce_pe_pack<256, 4, 4><<<1024, 256, 0, stream>>>(part, Eg, 16);

    // L2: CIN=256 COUT=128 8x8, SK=8 — grid (16, 2nb*4pc=8, 8), CPB=8
    gemm_mfma<256, 128, 8, 8, 8>
        <<<dim3(16, 8, 8), 256, 0, stream>>>(Eg, Bn2, part);
    reduce_pe_pack<128, 8, 8><<<2048, 256, 0, stream>>>(part, Eg, 8);

    // L3: CIN=128 COUT=64 16x16, SK=4 — grid (64, 1nb*4pc=4, 4), CPB=8
    gemm_mfma<128, 64, 16, 16, 4>
        <<<dim3(64, 4, 4), 256, 0, stream>>>(Eg, Bn3, part);
    reduce_p<64, 16, 16><<<4096, 256, 0, stream>>>(part, a3, 4);

    // L4: 32 channel groups x 2 q-halves (4096 blocks) + tanh reduce
    kan_l4_v9<<<4096, 256, 0, stream>>>(a3, wl4, p4);
    reduce_tanh_l4_32<<<768, 256, 0, stream>>>(p4, (float*)d_out);
  } else {
    // round-1 proven fallback (needs ~16.3 MB), original layout
    float* hF  = wsf;
    float* a1F = hF + 131072;
    float* a2F = a1F + 262144;
    float* a3F = a2F + 524288;
    float* partOld = a3F + 1048576;
    linear_relu_only<<<512, 256, 0, stream>>>(x, lin_w, lin_b, hF);
    kan_gemm<512, 256, 4, 4, 64, 8>
        <<<dim3(16, 4, 8), 256, 0, stream>>>(hF, bw1, sw1, ss1, partOld);
    reduce_partials_old<256, 4, 4, 8><<<1024, 256, 0, stream>>>(partOld, a1F);
    kan_gemm<256, 128, 8, 8, 64, 2>
        <<<dim3(64, 2, 2), 256, 0, stream>>>(a1F, bw2, sw2, ss2, partOld);
    reduce_partials_old<128, 8, 8, 2><<<2048, 256, 0, stream>>>(partOld, a2F);
    kan_gemm<128, 64, 16, 16, 64, 1>
        <<<dim3(256, 1, 1), 256, 0, stream>>>(a2F, bw3, sw3, ss3, a3F);
    kan_l4_split<<<1024, 256, 0, stream>>>(a3F, bw4, sw4, ss4, partOld);
    reduce_tanh_l4<<<768, 256, 0, stream>>>(partOld, (float*)d_out);
  }
}